// Round 1
// baseline (899.037 us; speedup 1.0000x reference)
//
#include <hip/hip_runtime.h>
#include <hip/hip_bf16.h>

// ---------------------------------------------------------------------------
// GraphSAGE 3-layer forward: per layer out = mean_agg(x) @ Wl^T + b + x @ Wr^T
// Strategy: build CSR (grouped by dst) once per launch, then per layer:
//   aggregate (node-parallel, one wave per node, gather-only) -> tiled GEMM.
// Final: log_softmax over 64 classes (one wave per node).
// ---------------------------------------------------------------------------

#define N_FEAT 128

// ---------------- degree histogram ----------------
__global__ void degree_kernel(const int* __restrict__ dst, int* __restrict__ cnt, int E) {
    int e = blockIdx.x * 256 + threadIdx.x;
    if (e < E) atomicAdd(&cnt[dst[e]], 1);
}

// ---------------- block inclusive scan helper ----------------
__device__ __forceinline__ int block_inclusive_scan(int v, int* lds_waves, int tid, int nthreads) {
    int lane = tid & 63;
    int wid  = tid >> 6;
#pragma unroll
    for (int d = 1; d < 64; d <<= 1) {
        int t = __shfl_up(v, d, 64);
        if (lane >= d) v += t;
    }
    if (lane == 63) lds_waves[wid] = v;
    __syncthreads();
    if (wid == 0) {
        int nw = nthreads >> 6;
        int s = (lane < nw) ? lds_waves[lane] : 0;
#pragma unroll
        for (int d = 1; d < 16; d <<= 1) {
            int t = __shfl_up(s, d, 64);
            if (lane >= d) s += t;
        }
        if (lane < nw) lds_waves[lane] = s;
    }
    __syncthreads();
    int add = (wid > 0) ? lds_waves[wid - 1] : 0;
    return v + add;
}

// pass 1: per-block exclusive scan + block sums
__global__ void scan1_kernel(const int* __restrict__ cnt, int* __restrict__ off_part,
                             int* __restrict__ blocksums, int n) {
    __shared__ int lds[16];
    int gid = blockIdx.x * 1024 + threadIdx.x;
    int v = (gid < n) ? cnt[gid] : 0;
    int incl = block_inclusive_scan(v, lds, threadIdx.x, 1024);
    if (gid < n) off_part[gid] = incl - v;
    if (threadIdx.x == 1023) blocksums[blockIdx.x] = incl;
}

// pass 2: scan block sums (nb <= 128), also write total to off[n]
__global__ void scan2_kernel(const int* __restrict__ blocksums, int* __restrict__ blockoffs,
                             int nb, int* __restrict__ off, int n) {
    __shared__ int lds[16];
    int v = (threadIdx.x < nb) ? blocksums[threadIdx.x] : 0;
    int incl = block_inclusive_scan(v, lds, (int)threadIdx.x, 128);
    if ((int)threadIdx.x < nb) blockoffs[threadIdx.x] = incl - v;
    if ((int)threadIdx.x == nb - 1) off[n] = incl;
}

// pass 3: add block offsets; also init cursor = off
__global__ void scan3_kernel(int* __restrict__ off, int* __restrict__ cursor,
                             const int* __restrict__ blockoffs, int n) {
    int gid = blockIdx.x * 256 + threadIdx.x;
    if (gid < n) {
        int o = off[gid] + blockoffs[gid >> 10];
        off[gid] = o;
        cursor[gid] = o;
    }
}

// counting-sort fill of CSR src lists
__global__ void fill_csr_kernel(const int* __restrict__ src, const int* __restrict__ dst,
                                int* __restrict__ cursor, int* __restrict__ csr, int E) {
    int e = blockIdx.x * 256 + threadIdx.x;
    if (e < E) {
        int d = dst[e];
        int pos = atomicAdd(&cursor[d], 1);
        csr[pos] = src[e];
    }
}

// ---------------- mean aggregation: one wave per node ----------------
__global__ void aggregate_kernel(const float* __restrict__ xin, const int* __restrict__ off,
                                 const int* __restrict__ csr, float* __restrict__ meanout, int n) {
    int node = blockIdx.x * 4 + (threadIdx.x >> 6);
    if (node >= n) return;
    int lane = threadIdx.x & 63;
    int s = off[node], e = off[node + 1];
    const float2* x2 = (const float2*)xin;
    float2 acc = make_float2(0.f, 0.f);
    int i = s;
    for (; i + 1 < e; i += 2) {
        int s0 = csr[i], s1 = csr[i + 1];
        float2 v0 = x2[(size_t)s0 * 64 + lane];
        float2 v1 = x2[(size_t)s1 * 64 + lane];
        acc.x += v0.x + v1.x;
        acc.y += v0.y + v1.y;
    }
    if (i < e) {
        float2 v = x2[(size_t)csr[i] * 64 + lane];
        acc.x += v.x;
        acc.y += v.y;
    }
    float inv = (e > s) ? 1.0f / (float)(e - s) : 0.f;
    float2* m2 = (float2*)meanout;
    m2[(size_t)node * 64 + lane] = make_float2(acc.x * inv, acc.y * inv);
}

// ---------------- fused dual GEMM: out = mean@Wl^T + h@Wr^T + b (opt ReLU) ----
// A-concat: [mean | h] (K=256), W-concat rows: Wl then Wr. Tiled 64 x HO.
template <int HO, bool RELU>
__global__ __launch_bounds__(256)
void sage_gemm_kernel(const float* __restrict__ Amean, const float* __restrict__ Ah,
                      const float* __restrict__ Wl, const float* __restrict__ Wr,
                      const float* __restrict__ bias, float* __restrict__ out, int n) {
    constexpr int BM = 64, BK = 32;
    constexpr int TX = HO / 4;      // threads along o (each covers 4 outputs)
    constexpr int TY = 256 / TX;    // threads along m
    constexpr int MPT = BM / TY;    // m per thread
    __shared__ float As[BK][BM + 1];   // [k][m]
    __shared__ float Ws[HO][BK + 1];   // [o][k]

    int tid = threadIdx.x;
    int tx = tid % TX, ty = tid / TX;
    int n0 = blockIdx.x * BM;

    float acc[MPT][4];
#pragma unroll
    for (int j = 0; j < MPT; ++j)
#pragma unroll
        for (int i = 0; i < 4; ++i) acc[j][i] = 0.f;

    for (int kc = 0; kc < 256; kc += BK) {
        const float* Aptr = (kc < 128) ? Amean : Ah;
        const float* Wptr = (kc < 128) ? Wl : Wr;
        int kbase = kc & 127;

        // A tile: 64 m x 32 k = 512 float4, 2 per thread
#pragma unroll
        for (int l = 0; l < 2; ++l) {
            int idx = tid + l * 256;
            int col4 = idx & 7, row = idx >> 3;
            int m = n0 + row;
            float4 v = make_float4(0.f, 0.f, 0.f, 0.f);
            if (m < n) v = *(const float4*)&Aptr[(size_t)m * 128 + kbase + col4 * 4];
            As[col4 * 4 + 0][row] = v.x;
            As[col4 * 4 + 1][row] = v.y;
            As[col4 * 4 + 2][row] = v.z;
            As[col4 * 4 + 3][row] = v.w;
        }
        // W tile: HO x 32 = HO*8 float4
#pragma unroll
        for (int l = 0; l < HO * 8 / 256; ++l) {
            int idx = tid + l * 256;
            int col4 = idx & 7, o = idx >> 3;
            float4 v = *(const float4*)&Wptr[(size_t)o * 128 + kbase + col4 * 4];
            Ws[o][col4 * 4 + 0] = v.x;
            Ws[o][col4 * 4 + 1] = v.y;
            Ws[o][col4 * 4 + 2] = v.z;
            Ws[o][col4 * 4 + 3] = v.w;
        }
        __syncthreads();

#pragma unroll 4
        for (int k = 0; k < BK; ++k) {
            float a[MPT], w[4];
#pragma unroll
            for (int j = 0; j < MPT; ++j) a[j] = As[k][ty * MPT + j];
#pragma unroll
            for (int i = 0; i < 4; ++i) w[i] = Ws[tx * 4 + i][k];
#pragma unroll
            for (int j = 0; j < MPT; ++j)
#pragma unroll
                for (int i = 0; i < 4; ++i) acc[j][i] += a[j] * w[i];
        }
        __syncthreads();
    }

    float b[4];
#pragma unroll
    for (int i = 0; i < 4; ++i) b[i] = bias[tx * 4 + i];
#pragma unroll
    for (int j = 0; j < MPT; ++j) {
        int m = n0 + ty * MPT + j;
        if (m < n) {
            float4 v;
            v.x = acc[j][0] + b[0];
            v.y = acc[j][1] + b[1];
            v.z = acc[j][2] + b[2];
            v.w = acc[j][3] + b[3];
            if (RELU) {
                v.x = fmaxf(v.x, 0.f); v.y = fmaxf(v.y, 0.f);
                v.z = fmaxf(v.z, 0.f); v.w = fmaxf(v.w, 0.f);
            }
            *(float4*)&out[(size_t)m * HO + tx * 4] = v;
        }
    }
}

// ---------------- log_softmax over 64 classes: one wave per node ----------------
__global__ void log_softmax64_kernel(const float* __restrict__ in, float* __restrict__ out, int n) {
    int node = blockIdx.x * 4 + (threadIdx.x >> 6);
    if (node >= n) return;
    int lane = threadIdx.x & 63;
    float v = in[(size_t)node * 64 + lane];
    float m = v;
#pragma unroll
    for (int d = 32; d >= 1; d >>= 1) m = fmaxf(m, __shfl_xor(m, d, 64));
    float ex = __expf(v - m);
    float s = ex;
#pragma unroll
    for (int d = 32; d >= 1; d >>= 1) s += __shfl_xor(s, d, 64);
    out[(size_t)node * 64 + lane] = v - m - logf(s);
}

extern "C" void kernel_launch(void* const* d_in, const int* in_sizes, int n_in,
                              void* d_out, int out_size, void* d_ws, size_t ws_size,
                              hipStream_t stream) {
    const float* x   = (const float*)d_in[0];
    const int*   ei  = (const int*)d_in[1];
    const float* W0l = (const float*)d_in[2];
    const float* b0  = (const float*)d_in[3];
    const float* W0r = (const float*)d_in[4];
    const float* W1l = (const float*)d_in[5];
    const float* b1  = (const float*)d_in[6];
    const float* W1r = (const float*)d_in[7];
    const float* W2l = (const float*)d_in[8];
    const float* b2  = (const float*)d_in[9];
    const float* W2r = (const float*)d_in[10];

    int n = in_sizes[0] / N_FEAT;       // 100000
    int E = in_sizes[1] / 2;            // 1600000
    const int* srcv = ei;
    const int* dstv = ei + E;

    // workspace layout
    char* ws = (char*)d_ws;
    int* off       = (int*)ws;              // n+1
    int* cursor    = off + (n + 1);         // n   (also used as cnt buffer)
    int* csr       = cursor + n;            // E
    int* blocksums = csr + E;               // 128
    int* blockoffs = blocksums + 128;       // 128
    size_t intbytes = ((size_t)(n + 1) + n + E + 256) * sizeof(int);
    intbytes = (intbytes + 255) & ~(size_t)255;
    float* meanbuf = (float*)(ws + intbytes);           // n*128
    float* hA      = meanbuf + (size_t)n * N_FEAT;      // n*128
    float* hB      = hA + (size_t)n * N_FEAT;           // n*128

    // ---- build CSR ----
    hipMemsetAsync(cursor, 0, (size_t)n * sizeof(int), stream);
    degree_kernel<<<(E + 255) / 256, 256, 0, stream>>>(dstv, cursor, E);
    int nb = (n + 1023) / 1024;
    scan1_kernel<<<nb, 1024, 0, stream>>>(cursor, off, blocksums, n);
    scan2_kernel<<<1, 128, 0, stream>>>(blocksums, blockoffs, nb, off, n);
    scan3_kernel<<<(n + 255) / 256, 256, 0, stream>>>(off, cursor, blockoffs, n);
    fill_csr_kernel<<<(E + 255) / 256, 256, 0, stream>>>(srcv, dstv, cursor, csr, E);

    int aggGrid = (n + 3) / 4;
    int gemmGrid = (n + 63) / 64;

    // ---- layer 1 ----
    aggregate_kernel<<<aggGrid, 256, 0, stream>>>(x, off, csr, meanbuf, n);
    sage_gemm_kernel<128, true><<<gemmGrid, 256, 0, stream>>>(meanbuf, x, W0l, W0r, b0, hA, n);
    // ---- layer 2 ----
    aggregate_kernel<<<aggGrid, 256, 0, stream>>>(hA, off, csr, meanbuf, n);
    sage_gemm_kernel<128, true><<<gemmGrid, 256, 0, stream>>>(meanbuf, hA, W1l, W1r, b1, hB, n);
    // ---- layer 3 ----
    aggregate_kernel<<<aggGrid, 256, 0, stream>>>(hB, off, csr, meanbuf, n);
    sage_gemm_kernel<64, false><<<gemmGrid, 256, 0, stream>>>(meanbuf, hB, W2l, W2r, b2, hA, n);
    // ---- log_softmax ----
    log_softmax64_kernel<<<(n + 3) / 4, 256, 0, stream>>>(hA, (float*)d_out, n);
}

// Round 2
// 649.635 us; speedup vs baseline: 1.3839x; 1.3839x over previous
//
#include <hip/hip_runtime.h>
#include <hip/hip_bf16.h>

// ---------------------------------------------------------------------------
// GraphSAGE 3-layer forward, bf16-MFMA edition.
//   per layer: out = mean_agg(h) @ Wl^T + b + h @ Wr^T   (ReLU between layers)
// CSR built once per launch; activations stored bf16; GEMMs use
// v_mfma_f32_16x16x32_bf16 with direct global fragment loads (no LDS).
// Layer 3 fuses bias + log_softmax into the GEMM epilogue.
// ---------------------------------------------------------------------------

#define N_FEAT 128

typedef __attribute__((ext_vector_type(8))) short short8;   // 8 bf16 = 4 VGPRs
typedef __attribute__((ext_vector_type(4))) float f32x4;

__device__ __forceinline__ ushort f2bf(float f) {
    union { float f; uint u; } v; v.f = f;
    uint u = v.u;
    return (ushort)((u + 0x7fffu + ((u >> 16) & 1u)) >> 16);   // RNE
}
__device__ __forceinline__ uint pack2bf(float x, float y) {
    return (uint)f2bf(x) | ((uint)f2bf(y) << 16);
}
__device__ __forceinline__ float bflo(uint v) {
    union { uint u; float f; } c; c.u = v << 16; return c.f;
}
__device__ __forceinline__ float bfhi(uint v) {
    union { uint u; float f; } c; c.u = v & 0xffff0000u; return c.f;
}

// ---------------- degree histogram ----------------
__global__ void degree_kernel(const int* __restrict__ dst, int* __restrict__ cnt, int E) {
    int e = blockIdx.x * 256 + threadIdx.x;
    if (e < E) atomicAdd(&cnt[dst[e]], 1);
}

// ---------------- block inclusive scan helper ----------------
__device__ __forceinline__ int block_inclusive_scan(int v, int* lds_waves, int tid, int nthreads) {
    int lane = tid & 63;
    int wid  = tid >> 6;
#pragma unroll
    for (int d = 1; d < 64; d <<= 1) {
        int t = __shfl_up(v, d, 64);
        if (lane >= d) v += t;
    }
    if (lane == 63) lds_waves[wid] = v;
    __syncthreads();
    if (wid == 0) {
        int nw = nthreads >> 6;
        int s = (lane < nw) ? lds_waves[lane] : 0;
#pragma unroll
        for (int d = 1; d < 16; d <<= 1) {
            int t = __shfl_up(s, d, 64);
            if (lane >= d) s += t;
        }
        if (lane < nw) lds_waves[lane] = s;
    }
    __syncthreads();
    int add = (wid > 0) ? lds_waves[wid - 1] : 0;
    return v + add;
}

__global__ void scan1_kernel(const int* __restrict__ cnt, int* __restrict__ off_part,
                             int* __restrict__ blocksums, int n) {
    __shared__ int lds[16];
    int gid = blockIdx.x * 1024 + threadIdx.x;
    int v = (gid < n) ? cnt[gid] : 0;
    int incl = block_inclusive_scan(v, lds, threadIdx.x, 1024);
    if (gid < n) off_part[gid] = incl - v;
    if (threadIdx.x == 1023) blocksums[blockIdx.x] = incl;
}

__global__ void scan2_kernel(const int* __restrict__ blocksums, int* __restrict__ blockoffs,
                             int nb, int* __restrict__ off, int n) {
    __shared__ int lds[16];
    int v = (threadIdx.x < nb) ? blocksums[threadIdx.x] : 0;
    int incl = block_inclusive_scan(v, lds, (int)threadIdx.x, 128);
    if ((int)threadIdx.x < nb) blockoffs[threadIdx.x] = incl - v;
    if ((int)threadIdx.x == nb - 1) off[n] = incl;
}

__global__ void scan3_kernel(int* __restrict__ off, int* __restrict__ cursor,
                             const int* __restrict__ blockoffs, int n) {
    int gid = blockIdx.x * 256 + threadIdx.x;
    if (gid < n) {
        int o = off[gid] + blockoffs[gid >> 10];
        off[gid] = o;
        cursor[gid] = o;
    }
}

__global__ void fill_csr_kernel(const int* __restrict__ src, const int* __restrict__ dst,
                                int* __restrict__ cursor, int* __restrict__ csr, int E) {
    int e = blockIdx.x * 256 + threadIdx.x;
    if (e < E) {
        int d = dst[e];
        int pos = atomicAdd(&cursor[d], 1);
        csr[pos] = src[e];
    }
}

// ---------------- fp32 -> bf16 conversions ----------------
__global__ void f32_to_bf16_kernel(const float* __restrict__ in, uint4* __restrict__ out, int total8) {
    int i = blockIdx.x * 256 + threadIdx.x;
    if (i >= total8) return;
    const float4* in4 = (const float4*)in;
    float4 a = in4[i * 2], b = in4[i * 2 + 1];
    uint4 o;
    o.x = pack2bf(a.x, a.y);
    o.y = pack2bf(a.z, a.w);
    o.z = pack2bf(b.x, b.y);
    o.w = pack2bf(b.z, b.w);
    out[i] = o;
}

// concat [Wl | Wr] -> bf16 [HO][256]
__global__ void wcat_kernel(const float* __restrict__ Wl, const float* __restrict__ Wr,
                            ushort* __restrict__ out, int HO) {
    int tid = blockIdx.x * 256 + threadIdx.x;     // over HO*64, 4 elems each
    if (tid >= HO * 64) return;
    int o = tid >> 6;
    int k4 = (tid & 63) * 4;
    const float* srcp = (k4 < 128) ? &Wl[(size_t)o * 128 + k4] : &Wr[(size_t)o * 128 + (k4 - 128)];
    float4 v = *(const float4*)srcp;
    uint2 p;
    p.x = pack2bf(v.x, v.y);
    p.y = pack2bf(v.z, v.w);
    *(uint2*)&out[(size_t)o * 256 + k4] = p;
}

// ---------------- mean aggregation (bf16 in/out): one wave per node ----------
__global__ void aggregate_bf16_kernel(const uint* __restrict__ x2, const int* __restrict__ off,
                                      const int* __restrict__ csr, uint* __restrict__ meanout, int n) {
    int node = blockIdx.x * 4 + (threadIdx.x >> 6);
    if (node >= n) return;
    int lane = threadIdx.x & 63;
    int s = off[node], e = off[node + 1];
    float ax = 0.f, ay = 0.f;
    int i = s;
    for (; i + 1 < e; i += 2) {
        uint v0 = x2[(size_t)csr[i] * 64 + lane];
        uint v1 = x2[(size_t)csr[i + 1] * 64 + lane];
        ax += bflo(v0) + bflo(v1);
        ay += bfhi(v0) + bfhi(v1);
    }
    if (i < e) {
        uint v = x2[(size_t)csr[i] * 64 + lane];
        ax += bflo(v);
        ay += bfhi(v);
    }
    float inv = (e > s) ? 1.0f / (float)(e - s) : 0.f;
    meanout[(size_t)node * 64 + lane] = pack2bf(ax * inv, ay * inv);
}

// ---------------- MFMA dual GEMM ----------------
// out[m][o] = sum_k [mean|h][m][k] * Wcat[o][k] + b[o]    (K=256, HO=CT*16)
// EPI 0: ReLU + bf16 store.  EPI 1: fused bias + log_softmax, f32 store.
// Each wave: 32 rows (2 x 16). Block = 4 waves = 128 rows.
template <int CT, int EPI>
__global__ __launch_bounds__(256)
void sage_mfma_kernel(const ushort* __restrict__ Amean, const ushort* __restrict__ Ah,
                      const ushort* __restrict__ W, const float* __restrict__ bias,
                      void* __restrict__ outp, int n) {
    constexpr int MREP = 2;
    int wid = threadIdx.x >> 6, lane = threadIdx.x & 63;
    int rowbase = blockIdx.x * 128 + wid * 32;
    int lr = lane & 15, kg = lane >> 4;

    f32x4 acc[MREP][CT];
#pragma unroll
    for (int mr = 0; mr < MREP; ++mr)
#pragma unroll
        for (int ct = 0; ct < CT; ++ct)
#pragma unroll
            for (int j = 0; j < 4; ++j) acc[mr][ct][j] = 0.f;

#pragma unroll
    for (int ks = 0; ks < 8; ++ks) {
        const ushort* Asrc = (ks < 4) ? Amean : Ah;
        int koff = (ks & 3) * 32 + kg * 8;
        short8 a[MREP];
#pragma unroll
        for (int mr = 0; mr < MREP; ++mr) {
            int r = rowbase + mr * 16 + lr;
            if (r > n - 1) r = n - 1;
            a[mr] = *(const short8*)&Asrc[(size_t)r * 128 + koff];
        }
#pragma unroll
        for (int ct = 0; ct < CT; ++ct) {
            short8 b = *(const short8*)&W[(size_t)(ct * 16 + lr) * 256 + ks * 32 + kg * 8];
#pragma unroll
            for (int mr = 0; mr < MREP; ++mr)
                acc[mr][ct] = __builtin_amdgcn_mfma_f32_16x16x32_bf16(a[mr], b, acc[mr][ct], 0, 0, 0);
        }
    }

    if (EPI == 0) {
        ushort* out = (ushort*)outp;
#pragma unroll
        for (int ct = 0; ct < CT; ++ct) {
            float b = bias[ct * 16 + lr];
#pragma unroll
            for (int mr = 0; mr < MREP; ++mr) {
#pragma unroll
                for (int j = 0; j < 4; ++j) {
                    int r = rowbase + mr * 16 + kg * 4 + j;
                    if (r < n) {
                        float v = fmaxf(acc[mr][ct][j] + b, 0.f);
                        out[(size_t)r * (CT * 16) + ct * 16 + lr] = f2bf(v);
                    }
                }
            }
        }
    } else {
        // CT == 4 here: each 16-lane group holds complete 64-class rows.
        float* out = (float*)outp;
#pragma unroll
        for (int mr = 0; mr < MREP; ++mr) {
            float v[4][4];
#pragma unroll
            for (int ct = 0; ct < 4; ++ct) {
                float b = bias[ct * 16 + lr];
#pragma unroll
                for (int j = 0; j < 4; ++j) v[ct][j] = acc[mr][ct][j] + b;
            }
#pragma unroll
            for (int j = 0; j < 4; ++j) {
                float m = fmaxf(fmaxf(v[0][j], v[1][j]), fmaxf(v[2][j], v[3][j]));
#pragma unroll
                for (int d = 1; d < 16; d <<= 1) m = fmaxf(m, __shfl_xor(m, d, 64));
                float s = __expf(v[0][j] - m) + __expf(v[1][j] - m) +
                          __expf(v[2][j] - m) + __expf(v[3][j] - m);
#pragma unroll
                for (int d = 1; d < 16; d <<= 1) s += __shfl_xor(s, d, 64);
                float ls = logf(s);
                int r = rowbase + mr * 16 + kg * 4 + j;
                if (r < n) {
#pragma unroll
                    for (int ct = 0; ct < 4; ++ct)
                        out[(size_t)r * 64 + ct * 16 + lr] = v[ct][j] - m - ls;
                }
            }
        }
    }
}

extern "C" void kernel_launch(void* const* d_in, const int* in_sizes, int n_in,
                              void* d_out, int out_size, void* d_ws, size_t ws_size,
                              hipStream_t stream) {
    const float* x   = (const float*)d_in[0];
    const int*   ei  = (const int*)d_in[1];
    const float* W0l = (const float*)d_in[2];
    const float* b0  = (const float*)d_in[3];
    const float* W0r = (const float*)d_in[4];
    const float* W1l = (const float*)d_in[5];
    const float* b1  = (const float*)d_in[6];
    const float* W1r = (const float*)d_in[7];
    const float* W2l = (const float*)d_in[8];
    const float* b2  = (const float*)d_in[9];
    const float* W2r = (const float*)d_in[10];

    int n = in_sizes[0] / N_FEAT;       // 100000
    int E = in_sizes[1] / 2;            // 1600000
    const int* srcv = ei;
    const int* dstv = ei + E;

    // workspace layout
    char* ws = (char*)d_ws;
    int* off       = (int*)ws;              // n+1
    int* cursor    = off + (n + 1);         // n (also degree count buffer)
    int* csr       = cursor + n;            // E
    int* blocksums = csr + E;               // 128
    int* blockoffs = blocksums + 128;       // 128
    size_t intbytes = ((size_t)(n + 1) + n + E + 256) * sizeof(int);
    intbytes = (intbytes + 255) & ~(size_t)255;
    ushort* xbf   = (ushort*)(ws + intbytes);       // n*128 bf16
    ushort* meanb = xbf + (size_t)n * N_FEAT;       // n*128
    ushort* hA    = meanb + (size_t)n * N_FEAT;     // n*128
    ushort* hB    = hA + (size_t)n * N_FEAT;        // n*128
    ushort* wcat0 = hB + (size_t)n * N_FEAT;        // 128*256
    ushort* wcat1 = wcat0 + 128 * 256;              // 128*256
    ushort* wcat2 = wcat1 + 128 * 256;              // 64*256

    // ---- build CSR ----
    hipMemsetAsync(cursor, 0, (size_t)n * sizeof(int), stream);
    degree_kernel<<<(E + 255) / 256, 256, 0, stream>>>(dstv, cursor, E);
    int nb = (n + 1023) / 1024;
    scan1_kernel<<<nb, 1024, 0, stream>>>(cursor, off, blocksums, n);
    scan2_kernel<<<1, 128, 0, stream>>>(blocksums, blockoffs, nb, off, n);
    scan3_kernel<<<(n + 255) / 256, 256, 0, stream>>>(off, cursor, blockoffs, n);
    fill_csr_kernel<<<(E + 255) / 256, 256, 0, stream>>>(srcv, dstv, cursor, csr, E);

    // ---- convert x and weights to bf16 ----
    int total8 = n * N_FEAT / 8;
    f32_to_bf16_kernel<<<(total8 + 255) / 256, 256, 0, stream>>>(x, (uint4*)xbf, total8);
    wcat_kernel<<<(128 * 64 + 255) / 256, 256, 0, stream>>>(W0l, W0r, wcat0, 128);
    wcat_kernel<<<(128 * 64 + 255) / 256, 256, 0, stream>>>(W1l, W1r, wcat1, 128);
    wcat_kernel<<<(64 * 64 + 255) / 256, 256, 0, stream>>>(W2l, W2r, wcat2, 64);

    int aggGrid = (n + 3) / 4;
    int gemmGrid = (n + 127) / 128;

    // ---- layer 1 ----
    aggregate_bf16_kernel<<<aggGrid, 256, 0, stream>>>((const uint*)xbf, off, csr, (uint*)meanb, n);
    sage_mfma_kernel<8, 0><<<gemmGrid, 256, 0, stream>>>(meanb, xbf, wcat0, b0, hA, n);
    // ---- layer 2 ----
    aggregate_bf16_kernel<<<aggGrid, 256, 0, stream>>>((const uint*)hA, off, csr, (uint*)meanb, n);
    sage_mfma_kernel<8, 0><<<gemmGrid, 256, 0, stream>>>(meanb, hA, wcat1, b1, hB, n);
    // ---- layer 3 (fused bias + log_softmax) ----
    aggregate_bf16_kernel<<<aggGrid, 256, 0, stream>>>((const uint*)hB, off, csr, (uint*)meanb, n);
    sage_mfma_kernel<4, 1><<<gemmGrid, 256, 0, stream>>>(meanb, hB, wcat2, b2, d_out, n);
}

// Round 3
// 556.375 us; speedup vs baseline: 1.6159x; 1.1676x over previous
//
#include <hip/hip_runtime.h>
#include <hip/hip_bf16.h>

// ---------------------------------------------------------------------------
// GraphSAGE 3-layer forward, bf16-MFMA + bucketed CSR build.
//   layer: out = mean_agg(h) @ Wl^T + b + h @ Wr^T   (ReLU between layers)
// CSR built via 2-level bucketed counting sort (write-locality friendly).
// Layer 3 uses transform-before-aggregate (mean is linear) to halve gathers,
// then fused add + log_softmax.
// ---------------------------------------------------------------------------

#define N_FEAT 128
#define NBMAX 512          // max coarse buckets (node width 256)
#define SCHUNK 2048        // edges per block in hist/scatter passes

typedef __attribute__((ext_vector_type(8))) short short8;   // 8 bf16 = 4 VGPRs
typedef __attribute__((ext_vector_type(4))) float f32x4;

__device__ __forceinline__ ushort f2bf(float f) {
    union { float f; uint u; } v; v.f = f;
    uint u = v.u;
    return (ushort)((u + 0x7fffu + ((u >> 16) & 1u)) >> 16);   // RNE
}
__device__ __forceinline__ uint pack2bf(float x, float y) {
    return (uint)f2bf(x) | ((uint)f2bf(y) << 16);
}
__device__ __forceinline__ float bflo(uint v) {
    union { uint u; float f; } c; c.u = v << 16; return c.f;
}
__device__ __forceinline__ float bfhi(uint v) {
    union { uint u; float f; } c; c.u = v & 0xffff0000u; return c.f;
}
__device__ __forceinline__ float bf1(ushort v) {
    union { uint u; float f; } c; c.u = ((uint)v) << 16; return c.f;
}

// ---------------- block inclusive scan helper ----------------
__device__ __forceinline__ int block_inclusive_scan(int v, int* lds_waves, int tid, int nthreads) {
    int lane = tid & 63;
    int wid  = tid >> 6;
#pragma unroll
    for (int d = 1; d < 64; d <<= 1) {
        int t = __shfl_up(v, d, 64);
        if (lane >= d) v += t;
    }
    if (lane == 63) lds_waves[wid] = v;
    __syncthreads();
    if (wid == 0) {
        int nw = nthreads >> 6;
        int s = (lane < nw) ? lds_waves[lane] : 0;
#pragma unroll
        for (int d = 1; d < 16; d <<= 1) {
            int t = __shfl_up(s, d, 64);
            if (lane >= d) s += t;
        }
        if (lane < nw) lds_waves[lane] = s;
    }
    __syncthreads();
    int add = (wid > 0) ? lds_waves[wid - 1] : 0;
    return v + add;
}

// ---------------- pass A: coarse-bucket histogram ----------------
__global__ void bucket_hist_kernel(const int* __restrict__ dst, int* __restrict__ btot,
                                   int E, int NB) {
    __shared__ int cnt[NBMAX];
    int tid = threadIdx.x;
    for (int i = tid; i < NB; i += 256) cnt[i] = 0;
    __syncthreads();
    int idx = blockIdx.x * SCHUNK + tid * 8;
    if (idx < E) {
        int4 d0 = *(const int4*)&dst[idx];
        int4 d1 = *(const int4*)&dst[idx + 4];
        atomicAdd(&cnt[d0.x >> 8], 1); atomicAdd(&cnt[d0.y >> 8], 1);
        atomicAdd(&cnt[d0.z >> 8], 1); atomicAdd(&cnt[d0.w >> 8], 1);
        atomicAdd(&cnt[d1.x >> 8], 1); atomicAdd(&cnt[d1.y >> 8], 1);
        atomicAdd(&cnt[d1.z >> 8], 1); atomicAdd(&cnt[d1.w >> 8], 1);
    }
    __syncthreads();
    for (int i = tid; i < NB; i += 256)
        if (cnt[i]) atomicAdd(&btot[i], cnt[i]);
}

// ---------------- scan bucket totals -> bases, init cursors ----------------
__global__ void bucket_scan_kernel(const int* __restrict__ btot, int* __restrict__ bbase,
                                   int* __restrict__ gcursor, int NB, int* __restrict__ off, int n) {
    __shared__ int lds[8];
    int t = threadIdx.x;
    int v = (t < NB) ? btot[t] : 0;
    int incl = block_inclusive_scan(v, lds, t, 512);
    if (t < NB) { bbase[t] = incl - v; gcursor[t] = incl - v; }
    if (t == NB - 1) { bbase[NB] = incl; off[n] = incl; }
}

// ---------------- pass B: scatter (src,dst) into coarse buckets ----------------
__global__ void bucket_scatter_kernel(const int* __restrict__ src, const int* __restrict__ dst,
                                      int* __restrict__ gcursor, uint2* __restrict__ bucketArr,
                                      int E, int NB) {
    __shared__ int cnt[NBMAX];
    __shared__ int gbase[NBMAX];
    int tid = threadIdx.x;
    for (int i = tid; i < NB; i += 256) cnt[i] = 0;
    __syncthreads();
    int idx = blockIdx.x * SCHUNK + tid * 8;
    int s[8], d[8], r[8];
    bool valid = (idx < E);
    if (valid) {
        int4 s0 = *(const int4*)&src[idx];
        int4 s1 = *(const int4*)&src[idx + 4];
        int4 d0 = *(const int4*)&dst[idx];
        int4 d1 = *(const int4*)&dst[idx + 4];
        s[0]=s0.x; s[1]=s0.y; s[2]=s0.z; s[3]=s0.w;
        s[4]=s1.x; s[5]=s1.y; s[6]=s1.z; s[7]=s1.w;
        d[0]=d0.x; d[1]=d0.y; d[2]=d0.z; d[3]=d0.w;
        d[4]=d1.x; d[5]=d1.y; d[6]=d1.z; d[7]=d1.w;
#pragma unroll
        for (int j = 0; j < 8; ++j) r[j] = atomicAdd(&cnt[d[j] >> 8], 1);
    }
    __syncthreads();
    for (int i = tid; i < NB; i += 256)
        if (cnt[i]) gbase[i] = atomicAdd(&gcursor[i], cnt[i]);
    __syncthreads();
    if (valid) {
#pragma unroll
        for (int j = 0; j < 8; ++j) {
            int b = d[j] >> 8;
            uint2 p; p.x = (uint)s[j]; p.y = (uint)d[j];
            bucketArr[(size_t)gbase[b] + r[j]] = p;
        }
    }
}

// ---------------- pass C: per-bucket CSR build (off + csr) ----------------
__global__ void bucket_build_kernel(const uint2* __restrict__ bucketArr, const int* __restrict__ bbase,
                                    int* __restrict__ off, int* __restrict__ csr, int n) {
    __shared__ int cnt[256];
    __shared__ int lds[4];
    int b = blockIdx.x, tid = threadIdx.x;
    int ebase = bbase[b], eend = bbase[b + 1];
    cnt[tid] = 0;
    __syncthreads();
    for (int i = ebase + tid; i < eend; i += 256) {
        uint2 p = bucketArr[i];
        atomicAdd(&cnt[p.y & 255], 1);
    }
    __syncthreads();
    int v = cnt[tid];
    int incl = block_inclusive_scan(v, lds, tid, 256);
    int excl = incl - v;
    int node = b * 256 + tid;
    if (node < n) off[node] = ebase + excl;
    __syncthreads();
    cnt[tid] = excl;
    __syncthreads();
    for (int i = ebase + tid; i < eend; i += 256) {
        uint2 p = bucketArr[i];
        int pos = ebase + atomicAdd(&cnt[p.y & 255], 1);
        csr[pos] = (int)p.x;
    }
}

// ---------------- fp32 -> bf16 conversions ----------------
__global__ void f32_to_bf16_kernel(const float* __restrict__ in, uint4* __restrict__ out, int total8) {
    int i = blockIdx.x * 256 + threadIdx.x;
    if (i >= total8) return;
    const float4* in4 = (const float4*)in;
    float4 a = in4[i * 2], b = in4[i * 2 + 1];
    uint4 o;
    o.x = pack2bf(a.x, a.y);
    o.y = pack2bf(a.z, a.w);
    o.z = pack2bf(b.x, b.y);
    o.w = pack2bf(b.z, b.w);
    out[i] = o;
}

// concat [Wl | Wr] -> bf16 [HO][256]
__global__ void wcat_kernel(const float* __restrict__ Wl, const float* __restrict__ Wr,
                            ushort* __restrict__ out, int HO) {
    int tid = blockIdx.x * 256 + threadIdx.x;     // over HO*64, 4 elems each
    if (tid >= HO * 64) return;
    int o = tid >> 6;
    int k4 = (tid & 63) * 4;
    const float* srcp = (k4 < 128) ? &Wl[(size_t)o * 128 + k4] : &Wr[(size_t)o * 128 + (k4 - 128)];
    float4 v = *(const float4*)srcp;
    uint2 p;
    p.x = pack2bf(v.x, v.y);
    p.y = pack2bf(v.z, v.w);
    *(uint2*)&out[(size_t)o * 256 + k4] = p;
}

// stack [W2l ; W2r] -> bf16 [128][128]
__global__ void wcat3_kernel(const float* __restrict__ W2l, const float* __restrict__ W2r,
                             ushort* __restrict__ out) {
    int tid = blockIdx.x * 256 + threadIdx.x;     // over 128*32, 4 elems each
    if (tid >= 128 * 32) return;
    int o = tid >> 5;
    int k4 = (tid & 31) * 4;
    const float* srcp = (o < 64) ? &W2l[(size_t)o * 128 + k4] : &W2r[(size_t)(o - 64) * 128 + k4];
    float4 v = *(const float4*)srcp;
    uint2 p;
    p.x = pack2bf(v.x, v.y);
    p.y = pack2bf(v.z, v.w);
    *(uint2*)&out[(size_t)o * 128 + k4] = p;
}

// ---------------- mean aggregation (bf16, 128-wide): one wave per node -------
__global__ void aggregate_bf16_kernel(const uint* __restrict__ x2, const int* __restrict__ off,
                                      const int* __restrict__ csr, uint* __restrict__ meanout, int n) {
    int node = blockIdx.x * 4 + (threadIdx.x >> 6);
    if (node >= n) return;
    int lane = threadIdx.x & 63;
    int s = off[node], e = off[node + 1];
    float ax = 0.f, ay = 0.f;
    int i = s;
    for (; i + 1 < e; i += 2) {
        uint v0 = x2[(size_t)csr[i] * 64 + lane];
        uint v1 = x2[(size_t)csr[i + 1] * 64 + lane];
        ax += bflo(v0) + bflo(v1);
        ay += bfhi(v0) + bfhi(v1);
    }
    if (i < e) {
        uint v = x2[(size_t)csr[i] * 64 + lane];
        ax += bflo(v);
        ay += bfhi(v);
    }
    float inv = (e > s) ? 1.0f / (float)(e - s) : 0.f;
    meanout[(size_t)node * 64 + lane] = pack2bf(ax * inv, ay * inv);
}

// ---------------- mean aggregation (bf16, 64-wide): 2 nodes per wave ---------
__global__ void aggregate64_kernel(const uint* __restrict__ p2, const int* __restrict__ off,
                                   const int* __restrict__ csr, float2* __restrict__ meanout, int n) {
    int wid = threadIdx.x >> 6, lane = threadIdx.x & 63;
    int node = blockIdx.x * 8 + wid * 2 + (lane >> 5);
    if (node >= n) return;
    int c = lane & 31;
    int s = off[node], e = off[node + 1];
    float ax = 0.f, ay = 0.f;
    for (int i = s; i < e; ++i) {
        uint v = p2[(size_t)csr[i] * 32 + c];
        ax += bflo(v);
        ay += bfhi(v);
    }
    float inv = (e > s) ? 1.0f / (float)(e - s) : 0.f;
    meanout[(size_t)node * 32 + c] = make_float2(ax * inv, ay * inv);
}

// ---------------- MFMA dual GEMM (layers 1-2) ----------------
// out[m][o] = sum_k [mean|h][m][k] * Wcat[o][k] + b[o], ReLU, bf16 store.
// K=256, HO=CT*16. Each wave: 32 rows. Block = 4 waves = 128 rows.
template <int CT>
__global__ __launch_bounds__(256)
void sage_mfma_kernel(const ushort* __restrict__ Amean, const ushort* __restrict__ Ah,
                      const ushort* __restrict__ W, const float* __restrict__ bias,
                      ushort* __restrict__ out, int n) {
    constexpr int MREP = 2;
    int wid = threadIdx.x >> 6, lane = threadIdx.x & 63;
    int rowbase = blockIdx.x * 128 + wid * 32;
    int lr = lane & 15, kg = lane >> 4;

    f32x4 acc[MREP][CT];
#pragma unroll
    for (int mr = 0; mr < MREP; ++mr)
#pragma unroll
        for (int ct = 0; ct < CT; ++ct)
#pragma unroll
            for (int j = 0; j < 4; ++j) acc[mr][ct][j] = 0.f;

#pragma unroll
    for (int ks = 0; ks < 8; ++ks) {
        const ushort* Asrc = (ks < 4) ? Amean : Ah;
        int koff = (ks & 3) * 32 + kg * 8;
        short8 a[MREP];
#pragma unroll
        for (int mr = 0; mr < MREP; ++mr) {
            int r = rowbase + mr * 16 + lr;
            if (r > n - 1) r = n - 1;
            a[mr] = *(const short8*)&Asrc[(size_t)r * 128 + koff];
        }
#pragma unroll
        for (int ct = 0; ct < CT; ++ct) {
            short8 b = *(const short8*)&W[(size_t)(ct * 16 + lr) * 256 + ks * 32 + kg * 8];
#pragma unroll
            for (int mr = 0; mr < MREP; ++mr)
                acc[mr][ct] = __builtin_amdgcn_mfma_f32_16x16x32_bf16(a[mr], b, acc[mr][ct], 0, 0, 0);
        }
    }

#pragma unroll
    for (int ct = 0; ct < CT; ++ct) {
        float b = bias[ct * 16 + lr];
#pragma unroll
        for (int mr = 0; mr < MREP; ++mr) {
#pragma unroll
            for (int j = 0; j < 4; ++j) {
                int r = rowbase + mr * 16 + kg * 4 + j;
                if (r < n) {
                    float v = fmaxf(acc[mr][ct][j] + b, 0.f);
                    out[(size_t)r * (CT * 16) + ct * 16 + lr] = f2bf(v);
                }
            }
        }
    }
}

// ---------------- layer-3 transform GEMM: p = h@W2l^T, q = h@W2r^T + b2 ------
// W3 = [W2l ; W2r] as [128][128]. K=128, CT=8 col tiles; cols 0-63 -> p, 64-127 -> q.
__global__ __launch_bounds__(256)
void gemm3_kernel(const ushort* __restrict__ Ah, const ushort* __restrict__ W,
                  const float* __restrict__ b2, ushort* __restrict__ p,
                  ushort* __restrict__ q, int n) {
    constexpr int MREP = 2, CT = 8;
    int wid = threadIdx.x >> 6, lane = threadIdx.x & 63;
    int rowbase = blockIdx.x * 128 + wid * 32;
    int lr = lane & 15, kg = lane >> 4;

    f32x4 acc[MREP][CT];
#pragma unroll
    for (int mr = 0; mr < MREP; ++mr)
#pragma unroll
        for (int ct = 0; ct < CT; ++ct)
#pragma unroll
            for (int j = 0; j < 4; ++j) acc[mr][ct][j] = 0.f;

#pragma unroll
    for (int ks = 0; ks < 4; ++ks) {
        int koff = ks * 32 + kg * 8;
        short8 a[MREP];
#pragma unroll
        for (int mr = 0; mr < MREP; ++mr) {
            int r = rowbase + mr * 16 + lr;
            if (r > n - 1) r = n - 1;
            a[mr] = *(const short8*)&Ah[(size_t)r * 128 + koff];
        }
#pragma unroll
        for (int ct = 0; ct < CT; ++ct) {
            short8 b = *(const short8*)&W[(size_t)(ct * 16 + lr) * 128 + koff];
#pragma unroll
            for (int mr = 0; mr < MREP; ++mr)
                acc[mr][ct] = __builtin_amdgcn_mfma_f32_16x16x32_bf16(a[mr], b, acc[mr][ct], 0, 0, 0);
        }
    }

#pragma unroll
    for (int ct = 0; ct < CT; ++ct) {
        bool isq = (ct >= 4);
        float b = isq ? b2[(ct - 4) * 16 + lr] : 0.f;
        ushort* dstp = isq ? q : p;
        int col = (isq ? (ct - 4) : ct) * 16 + lr;
#pragma unroll
        for (int mr = 0; mr < MREP; ++mr) {
#pragma unroll
            for (int j = 0; j < 4; ++j) {
                int r = rowbase + mr * 16 + kg * 4 + j;
                if (r < n) dstp[(size_t)r * 64 + col] = f2bf(acc[mr][ct][j] + b);
            }
        }
    }
}

// ---------------- final: out = log_softmax(mean_p + q) ----------------
__global__ void final_ls_kernel(const float* __restrict__ meanp, const ushort* __restrict__ q,
                                float* __restrict__ out, int n) {
    int node = blockIdx.x * 4 + (threadIdx.x >> 6);
    if (node >= n) return;
    int lane = threadIdx.x & 63;
    float v = meanp[(size_t)node * 64 + lane] + bf1(q[(size_t)node * 64 + lane]);
    float m = v;
#pragma unroll
    for (int d = 32; d >= 1; d >>= 1) m = fmaxf(m, __shfl_xor(m, d, 64));
    float ex = __expf(v - m);
    float s = ex;
#pragma unroll
    for (int d = 32; d >= 1; d >>= 1) s += __shfl_xor(s, d, 64);
    out[(size_t)node * 64 + lane] = v - m - logf(s);
}

extern "C" void kernel_launch(void* const* d_in, const int* in_sizes, int n_in,
                              void* d_out, int out_size, void* d_ws, size_t ws_size,
                              hipStream_t stream) {
    const float* x   = (const float*)d_in[0];
    const int*   ei  = (const int*)d_in[1];
    const float* W0l = (const float*)d_in[2];
    const float* b0  = (const float*)d_in[3];
    const float* W0r = (const float*)d_in[4];
    const float* W1l = (const float*)d_in[5];
    const float* b1  = (const float*)d_in[6];
    const float* W1r = (const float*)d_in[7];
    const float* W2l = (const float*)d_in[8];
    const float* b2  = (const float*)d_in[9];
    const float* W2r = (const float*)d_in[10];

    int n = in_sizes[0] / N_FEAT;       // 100000
    int E = in_sizes[1] / 2;            // 1600000
    const int* srcv = ei;
    const int* dstv = ei + E;
    int NB = (n + 255) >> 8;            // coarse buckets (width 256 nodes)

    // workspace layout
    char* ws = (char*)d_ws;
    int* off     = (int*)ws;                 // n+1
    int* csr     = off + (n + 1);            // E
    int* btot    = csr + E;                  // NB
    int* bbase   = btot + NBMAX;             // NB+1
    int* gcursor = bbase + NBMAX + 1;        // NB
    size_t intbytes = ((size_t)(n + 1) + E + 3 * NBMAX + 1) * sizeof(int);
    intbytes = (intbytes + 255) & ~(size_t)255;
    ushort* xbf   = (ushort*)(ws + intbytes);       // n*128 bf16
    ushort* meanb = xbf + (size_t)n * N_FEAT;       // n*128  (also: bucketArr, p3|q3)
    ushort* hA    = meanb + (size_t)n * N_FEAT;     // n*128  (also: meanp f32 [n][64])
    ushort* hB    = hA + (size_t)n * N_FEAT;        // n*128
    ushort* wcat0 = hB + (size_t)n * N_FEAT;        // 128*256
    ushort* wcat1 = wcat0 + 128 * 256;              // 128*256
    ushort* wcat3 = wcat1 + 128 * 256;              // 128*128

    uint2* bucketArr = (uint2*)meanb;               // E * 8B, used only during CSR build
    ushort* p3 = meanb;                             // n*64 bf16
    ushort* q3 = meanb + (size_t)n * 64;            // n*64 bf16
    float2* meanp = (float2*)hA;                    // n*64 f32 (as float2[n*32])

    int ebGrid = (E + SCHUNK - 1) / SCHUNK;

    // ---- build CSR (bucketed counting sort) ----
    hipMemsetAsync(btot, 0, (size_t)NBMAX * sizeof(int), stream);
    bucket_hist_kernel<<<ebGrid, 256, 0, stream>>>(dstv, btot, E, NB);
    bucket_scan_kernel<<<1, 512, 0, stream>>>(btot, bbase, gcursor, NB, off, n);
    bucket_scatter_kernel<<<ebGrid, 256, 0, stream>>>(srcv, dstv, gcursor, bucketArr, E, NB);
    bucket_build_kernel<<<NB, 256, 0, stream>>>(bucketArr, bbase, off, csr, n);

    // ---- convert x and weights to bf16 ----
    int total8 = n * N_FEAT / 8;
    f32_to_bf16_kernel<<<(total8 + 255) / 256, 256, 0, stream>>>(x, (uint4*)xbf, total8);
    wcat_kernel<<<(128 * 64 + 255) / 256, 256, 0, stream>>>(W0l, W0r, wcat0, 128);
    wcat_kernel<<<(128 * 64 + 255) / 256, 256, 0, stream>>>(W1l, W1r, wcat1, 128);
    wcat3_kernel<<<(128 * 32 + 255) / 256, 256, 0, stream>>>(W2l, W2r, wcat3);

    int aggGrid = (n + 3) / 4;
    int gemmGrid = (n + 127) / 128;

    // ---- layer 1 ----
    aggregate_bf16_kernel<<<aggGrid, 256, 0, stream>>>((const uint*)xbf, off, csr, (uint*)meanb, n);
    sage_mfma_kernel<8><<<gemmGrid, 256, 0, stream>>>(meanb, xbf, wcat0, b0, hA, n);
    // ---- layer 2 ----
    aggregate_bf16_kernel<<<aggGrid, 256, 0, stream>>>((const uint*)hA, off, csr, (uint*)meanb, n);
    sage_mfma_kernel<8><<<gemmGrid, 256, 0, stream>>>(meanb, hA, wcat1, b1, hB, n);
    // ---- layer 3: transform first, then aggregate 64-wide ----
    gemm3_kernel<<<gemmGrid, 256, 0, stream>>>(hB, wcat3, b2, p3, q3, n);
    aggregate64_kernel<<<(n + 7) / 8, 256, 0, stream>>>((const uint*)p3, off, csr, meanp, n);
    final_ls_kernel<<<(n + 3) / 4, 256, 0, stream>>>((const float*)meanp, q3, (float*)d_out, n);
}

// Round 4
// 433.151 us; speedup vs baseline: 2.0756x; 1.2845x over previous
//
#include <hip/hip_runtime.h>
#include <hip/hip_bf16.h>

// ---------------------------------------------------------------------------
// GraphSAGE 3-layer forward, bf16-MFMA + bucketed CSR build.
//   layer: out = mean_agg(h) @ Wl^T + b + h @ Wr^T   (ReLU between layers)
// CSR built via 2-level bucketed counting sort (write-locality friendly,
// packed uint entries). Aggregation gathers 16 B/lane (whole row per 16-lane
// group) for high bytes-in-flight. Layer 3 transforms before aggregating.
// ---------------------------------------------------------------------------

#define N_FEAT 128
#define NBMAX 512          // max coarse buckets (node width 256)
#define SCHUNK 2048        // edges per block in hist/scatter passes

typedef __attribute__((ext_vector_type(8))) short short8;   // 8 bf16 = 4 VGPRs
typedef __attribute__((ext_vector_type(4))) float f32x4;

__device__ __forceinline__ ushort f2bf(float f) {
    union { float f; uint u; } v; v.f = f;
    uint u = v.u;
    return (ushort)((u + 0x7fffu + ((u >> 16) & 1u)) >> 16);   // RNE
}
__device__ __forceinline__ uint pack2bf(float x, float y) {
    return (uint)f2bf(x) | ((uint)f2bf(y) << 16);
}
__device__ __forceinline__ float bflo(uint v) {
    union { uint u; float f; } c; c.u = v << 16; return c.f;
}
__device__ __forceinline__ float bfhi(uint v) {
    union { uint u; float f; } c; c.u = v & 0xffff0000u; return c.f;
}
__device__ __forceinline__ float bf1(ushort v) {
    union { uint u; float f; } c; c.u = ((uint)v) << 16; return c.f;
}

// ---------------- block inclusive scan helper ----------------
__device__ __forceinline__ int block_inclusive_scan(int v, int* lds_waves, int tid, int nthreads) {
    int lane = tid & 63;
    int wid  = tid >> 6;
#pragma unroll
    for (int d = 1; d < 64; d <<= 1) {
        int t = __shfl_up(v, d, 64);
        if (lane >= d) v += t;
    }
    if (lane == 63) lds_waves[wid] = v;
    __syncthreads();
    if (wid == 0) {
        int nw = nthreads >> 6;
        int s = (lane < nw) ? lds_waves[lane] : 0;
#pragma unroll
        for (int d = 1; d < 16; d <<= 1) {
            int t = __shfl_up(s, d, 64);
            if (lane >= d) s += t;
        }
        if (lane < nw) lds_waves[lane] = s;
    }
    __syncthreads();
    int add = (wid > 0) ? lds_waves[wid - 1] : 0;
    return v + add;
}

// ---------------- pass A: coarse-bucket histogram ----------------
__global__ void bucket_hist_kernel(const int* __restrict__ dst, int* __restrict__ btot,
                                   int E, int NB) {
    __shared__ int cnt[NBMAX];
    int tid = threadIdx.x;
    for (int i = tid; i < NB; i += 256) cnt[i] = 0;
    __syncthreads();
    int idx = blockIdx.x * SCHUNK + tid * 8;
    if (idx < E) {
        int4 d0 = *(const int4*)&dst[idx];
        int4 d1 = *(const int4*)&dst[idx + 4];
        atomicAdd(&cnt[d0.x >> 8], 1); atomicAdd(&cnt[d0.y >> 8], 1);
        atomicAdd(&cnt[d0.z >> 8], 1); atomicAdd(&cnt[d0.w >> 8], 1);
        atomicAdd(&cnt[d1.x >> 8], 1); atomicAdd(&cnt[d1.y >> 8], 1);
        atomicAdd(&cnt[d1.z >> 8], 1); atomicAdd(&cnt[d1.w >> 8], 1);
    }
    __syncthreads();
    for (int i = tid; i < NB; i += 256)
        if (cnt[i]) atomicAdd(&btot[i], cnt[i]);
}

// ---------------- scan bucket totals -> bases, init cursors ----------------
__global__ void bucket_scan_kernel(const int* __restrict__ btot, int* __restrict__ bbase,
                                   int* __restrict__ gcursor, int NB, int* __restrict__ off, int n) {
    __shared__ int lds[8];
    int t = threadIdx.x;
    int v = (t < NB) ? btot[t] : 0;
    int incl = block_inclusive_scan(v, lds, t, 512);
    if (t < NB) { bbase[t] = incl - v; gcursor[t] = incl - v; }
    if (t == NB - 1) { bbase[NB] = incl; off[n] = incl; }
}

// ---------------- pass B: scatter packed (dloc<<24|src) into buckets --------
__global__ void bucket_scatter_kernel(const int* __restrict__ src, const int* __restrict__ dst,
                                      int* __restrict__ gcursor, uint* __restrict__ bucketArr,
                                      int E, int NB) {
    __shared__ int cnt[NBMAX];
    __shared__ int gbase[NBMAX];
    int tid = threadIdx.x;
    for (int i = tid; i < NB; i += 256) cnt[i] = 0;
    __syncthreads();
    int idx = blockIdx.x * SCHUNK + tid * 8;
    int s[8], d[8], r[8];
    bool valid = (idx < E);
    if (valid) {
        int4 s0 = *(const int4*)&src[idx];
        int4 s1 = *(const int4*)&src[idx + 4];
        int4 d0 = *(const int4*)&dst[idx];
        int4 d1 = *(const int4*)&dst[idx + 4];
        s[0]=s0.x; s[1]=s0.y; s[2]=s0.z; s[3]=s0.w;
        s[4]=s1.x; s[5]=s1.y; s[6]=s1.z; s[7]=s1.w;
        d[0]=d0.x; d[1]=d0.y; d[2]=d0.z; d[3]=d0.w;
        d[4]=d1.x; d[5]=d1.y; d[6]=d1.z; d[7]=d1.w;
#pragma unroll
        for (int j = 0; j < 8; ++j) r[j] = atomicAdd(&cnt[d[j] >> 8], 1);
    }
    __syncthreads();
    for (int i = tid; i < NB; i += 256)
        if (cnt[i]) gbase[i] = atomicAdd(&gcursor[i], cnt[i]);
    __syncthreads();
    if (valid) {
#pragma unroll
        for (int j = 0; j < 8; ++j) {
            int b = d[j] >> 8;
            uint p = ((uint)(d[j] & 255) << 24) | (uint)s[j];
            bucketArr[(size_t)gbase[b] + r[j]] = p;
        }
    }
}

// ---------------- pass C: per-bucket CSR build (off + csr) ----------------
__global__ void bucket_build_kernel(const uint* __restrict__ bucketArr, const int* __restrict__ bbase,
                                    int* __restrict__ off, int* __restrict__ csr, int n) {
    __shared__ int cnt[256];
    __shared__ int lds[4];
    int b = blockIdx.x, tid = threadIdx.x;
    int ebase = bbase[b], eend = bbase[b + 1];
    cnt[tid] = 0;
    __syncthreads();
    for (int i = ebase + tid; i < eend; i += 256) {
        uint p = bucketArr[i];
        atomicAdd(&cnt[p >> 24], 1);
    }
    __syncthreads();
    int v = cnt[tid];
    int incl = block_inclusive_scan(v, lds, tid, 256);
    int excl = incl - v;
    int node = b * 256 + tid;
    if (node < n) off[node] = ebase + excl;
    __syncthreads();
    cnt[tid] = excl;
    __syncthreads();
    for (int i = ebase + tid; i < eend; i += 256) {
        uint p = bucketArr[i];
        int pos = ebase + atomicAdd(&cnt[p >> 24], 1);
        csr[pos] = (int)(p & 0xFFFFFFu);
    }
}

// ---------------- fp32 -> bf16 conversions ----------------
__global__ void f32_to_bf16_kernel(const float* __restrict__ in, uint4* __restrict__ out, int total8) {
    int i = blockIdx.x * 256 + threadIdx.x;
    if (i >= total8) return;
    const float4* in4 = (const float4*)in;
    float4 a = in4[i * 2], b = in4[i * 2 + 1];
    uint4 o;
    o.x = pack2bf(a.x, a.y);
    o.y = pack2bf(a.z, a.w);
    o.z = pack2bf(b.x, b.y);
    o.w = pack2bf(b.z, b.w);
    out[i] = o;
}

// concat [Wl | Wr] -> bf16 [HO][256]
__global__ void wcat_kernel(const float* __restrict__ Wl, const float* __restrict__ Wr,
                            ushort* __restrict__ out, int HO) {
    int tid = blockIdx.x * 256 + threadIdx.x;     // over HO*64, 4 elems each
    if (tid >= HO * 64) return;
    int o = tid >> 6;
    int k4 = (tid & 63) * 4;
    const float* srcp = (k4 < 128) ? &Wl[(size_t)o * 128 + k4] : &Wr[(size_t)o * 128 + (k4 - 128)];
    float4 v = *(const float4*)srcp;
    uint2 p;
    p.x = pack2bf(v.x, v.y);
    p.y = pack2bf(v.z, v.w);
    *(uint2*)&out[(size_t)o * 256 + k4] = p;
}

// stack [W2l ; W2r] -> bf16 [128][128]
__global__ void wcat3_kernel(const float* __restrict__ W2l, const float* __restrict__ W2r,
                             ushort* __restrict__ out) {
    int tid = blockIdx.x * 256 + threadIdx.x;     // over 128*32, 4 elems each
    if (tid >= 128 * 32) return;
    int o = tid >> 5;
    int k4 = (tid & 31) * 4;
    const float* srcp = (o < 64) ? &W2l[(size_t)o * 128 + k4] : &W2r[(size_t)(o - 64) * 128 + k4];
    float4 v = *(const float4*)srcp;
    uint2 p;
    p.x = pack2bf(v.x, v.y);
    p.y = pack2bf(v.z, v.w);
    *(uint2*)&out[(size_t)o * 128 + k4] = p;
}

// ---------------- mean aggregation (bf16 128-wide), 16 B/lane gathers --------
// One wave per node; 4 x 16-lane groups each read a whole 256 B neighbor row.
__global__ void aggregate128_kernel(const uint4* __restrict__ x4, const int* __restrict__ off,
                                    const int* __restrict__ csr, uint4* __restrict__ meanout, int n) {
    int node = blockIdx.x * 4 + (threadIdx.x >> 6);
    if (node >= n) return;
    int lane = threadIdx.x & 63;
    int g = lane >> 4, lr = lane & 15;
    int s = off[node], e = off[node + 1];
    float acc[8];
#pragma unroll
    for (int j = 0; j < 8; ++j) acc[j] = 0.f;

    int i = s + g;
    for (; i + 4 < e; i += 8) {
        int s0 = csr[i], s1 = csr[i + 4];
        uint4 v0 = x4[(size_t)s0 * 16 + lr];
        uint4 v1 = x4[(size_t)s1 * 16 + lr];
        acc[0] += bflo(v0.x) + bflo(v1.x);
        acc[1] += bfhi(v0.x) + bfhi(v1.x);
        acc[2] += bflo(v0.y) + bflo(v1.y);
        acc[3] += bfhi(v0.y) + bfhi(v1.y);
        acc[4] += bflo(v0.z) + bflo(v1.z);
        acc[5] += bfhi(v0.z) + bfhi(v1.z);
        acc[6] += bflo(v0.w) + bflo(v1.w);
        acc[7] += bfhi(v0.w) + bfhi(v1.w);
    }
    if (i < e) {
        uint4 v = x4[(size_t)csr[i] * 16 + lr];
        acc[0] += bflo(v.x); acc[1] += bfhi(v.x);
        acc[2] += bflo(v.y); acc[3] += bfhi(v.y);
        acc[4] += bflo(v.z); acc[5] += bfhi(v.z);
        acc[6] += bflo(v.w); acc[7] += bfhi(v.w);
    }
    // reduce across the 4 groups (lanes differing in bits 4,5)
#pragma unroll
    for (int j = 0; j < 8; ++j) {
        acc[j] += __shfl_xor(acc[j], 16, 64);
        acc[j] += __shfl_xor(acc[j], 32, 64);
    }
    if (g == 0) {
        float inv = (e > s) ? 1.0f / (float)(e - s) : 0.f;
        uint4 o;
        o.x = pack2bf(acc[0] * inv, acc[1] * inv);
        o.y = pack2bf(acc[2] * inv, acc[3] * inv);
        o.z = pack2bf(acc[4] * inv, acc[5] * inv);
        o.w = pack2bf(acc[6] * inv, acc[7] * inv);
        meanout[(size_t)node * 16 + lr] = o;
    }
}

// ---------------- mean aggregation (bf16 64-wide -> f32), layer 3 ------------
// One wave per node; 8 x 8-lane groups each read a whole 128 B row.
__global__ void aggregate64_kernel(const uint4* __restrict__ p4, const int* __restrict__ off,
                                   const int* __restrict__ csr, float4* __restrict__ meanout, int n) {
    int node = blockIdx.x * 4 + (threadIdx.x >> 6);
    if (node >= n) return;
    int lane = threadIdx.x & 63;
    int g = lane >> 3, lr = lane & 7;
    int s = off[node], e = off[node + 1];
    float acc[8];
#pragma unroll
    for (int j = 0; j < 8; ++j) acc[j] = 0.f;

    int i = s + g;
    for (; i + 8 < e; i += 16) {
        int s0 = csr[i], s1 = csr[i + 8];
        uint4 v0 = p4[(size_t)s0 * 8 + lr];
        uint4 v1 = p4[(size_t)s1 * 8 + lr];
        acc[0] += bflo(v0.x) + bflo(v1.x);
        acc[1] += bfhi(v0.x) + bfhi(v1.x);
        acc[2] += bflo(v0.y) + bflo(v1.y);
        acc[3] += bfhi(v0.y) + bfhi(v1.y);
        acc[4] += bflo(v0.z) + bflo(v1.z);
        acc[5] += bfhi(v0.z) + bfhi(v1.z);
        acc[6] += bflo(v0.w) + bflo(v1.w);
        acc[7] += bfhi(v0.w) + bfhi(v1.w);
    }
    if (i < e) {
        uint4 v = p4[(size_t)csr[i] * 8 + lr];
        acc[0] += bflo(v.x); acc[1] += bfhi(v.x);
        acc[2] += bflo(v.y); acc[3] += bfhi(v.y);
        acc[4] += bflo(v.z); acc[5] += bfhi(v.z);
        acc[6] += bflo(v.w); acc[7] += bfhi(v.w);
    }
#pragma unroll
    for (int j = 0; j < 8; ++j) {
        acc[j] += __shfl_xor(acc[j], 8, 64);
        acc[j] += __shfl_xor(acc[j], 16, 64);
        acc[j] += __shfl_xor(acc[j], 32, 64);
    }
    if (g == 0) {
        float inv = (e > s) ? 1.0f / (float)(e - s) : 0.f;
        float4 o0, o1;
        o0.x = acc[0] * inv; o0.y = acc[1] * inv; o0.z = acc[2] * inv; o0.w = acc[3] * inv;
        o1.x = acc[4] * inv; o1.y = acc[5] * inv; o1.z = acc[6] * inv; o1.w = acc[7] * inv;
        meanout[(size_t)node * 16 + lr * 2]     = o0;
        meanout[(size_t)node * 16 + lr * 2 + 1] = o1;
    }
}

// ---------------- MFMA dual GEMM (layers 1-2) ----------------
// out[m][o] = sum_k [mean|h][m][k] * Wcat[o][k] + b[o], ReLU, bf16 store.
// K=256, HO=CT*16. Each wave: 32 rows. Block = 4 waves = 128 rows.
template <int CT>
__global__ __launch_bounds__(256)
void sage_mfma_kernel(const ushort* __restrict__ Amean, const ushort* __restrict__ Ah,
                      const ushort* __restrict__ W, const float* __restrict__ bias,
                      ushort* __restrict__ out, int n) {
    constexpr int MREP = 2;
    int wid = threadIdx.x >> 6, lane = threadIdx.x & 63;
    int rowbase = blockIdx.x * 128 + wid * 32;
    int lr = lane & 15, kg = lane >> 4;

    f32x4 acc[MREP][CT];
#pragma unroll
    for (int mr = 0; mr < MREP; ++mr)
#pragma unroll
        for (int ct = 0; ct < CT; ++ct)
#pragma unroll
            for (int j = 0; j < 4; ++j) acc[mr][ct][j] = 0.f;

#pragma unroll
    for (int ks = 0; ks < 8; ++ks) {
        const ushort* Asrc = (ks < 4) ? Amean : Ah;
        int koff = (ks & 3) * 32 + kg * 8;
        short8 a[MREP];
#pragma unroll
        for (int mr = 0; mr < MREP; ++mr) {
            int r = rowbase + mr * 16 + lr;
            if (r > n - 1) r = n - 1;
            a[mr] = *(const short8*)&Asrc[(size_t)r * 128 + koff];
        }
#pragma unroll
        for (int ct = 0; ct < CT; ++ct) {
            short8 b = *(const short8*)&W[(size_t)(ct * 16 + lr) * 256 + ks * 32 + kg * 8];
#pragma unroll
            for (int mr = 0; mr < MREP; ++mr)
                acc[mr][ct] = __builtin_amdgcn_mfma_f32_16x16x32_bf16(a[mr], b, acc[mr][ct], 0, 0, 0);
        }
    }

#pragma unroll
    for (int ct = 0; ct < CT; ++ct) {
        float b = bias[ct * 16 + lr];
#pragma unroll
        for (int mr = 0; mr < MREP; ++mr) {
#pragma unroll
            for (int j = 0; j < 4; ++j) {
                int r = rowbase + mr * 16 + kg * 4 + j;
                if (r < n) {
                    float v = fmaxf(acc[mr][ct][j] + b, 0.f);
                    out[(size_t)r * (CT * 16) + ct * 16 + lr] = f2bf(v);
                }
            }
        }
    }
}

// ---------------- layer-3 transform GEMM: p = h@W2l^T, q = h@W2r^T + b2 ------
// W3 = [W2l ; W2r] as [128][128]. K=128, CT=8 col tiles; cols 0-63 -> p, 64-127 -> q.
__global__ __launch_bounds__(256)
void gemm3_kernel(const ushort* __restrict__ Ah, const ushort* __restrict__ W,
                  const float* __restrict__ b2, ushort* __restrict__ p,
                  ushort* __restrict__ q, int n) {
    constexpr int MREP = 2, CT = 8;
    int wid = threadIdx.x >> 6, lane = threadIdx.x & 63;
    int rowbase = blockIdx.x * 128 + wid * 32;
    int lr = lane & 15, kg = lane >> 4;

    f32x4 acc[MREP][CT];
#pragma unroll
    for (int mr = 0; mr < MREP; ++mr)
#pragma unroll
        for (int ct = 0; ct < CT; ++ct)
#pragma unroll
            for (int j = 0; j < 4; ++j) acc[mr][ct][j] = 0.f;

#pragma unroll
    for (int ks = 0; ks < 4; ++ks) {
        int koff = ks * 32 + kg * 8;
        short8 a[MREP];
#pragma unroll
        for (int mr = 0; mr < MREP; ++mr) {
            int r = rowbase + mr * 16 + lr;
            if (r > n - 1) r = n - 1;
            a[mr] = *(const short8*)&Ah[(size_t)r * 128 + koff];
        }
#pragma unroll
        for (int ct = 0; ct < CT; ++ct) {
            short8 b = *(const short8*)&W[(size_t)(ct * 16 + lr) * 128 + koff];
#pragma unroll
            for (int mr = 0; mr < MREP; ++mr)
                acc[mr][ct] = __builtin_amdgcn_mfma_f32_16x16x32_bf16(a[mr], b, acc[mr][ct], 0, 0, 0);
        }
    }

#pragma unroll
    for (int ct = 0; ct < CT; ++ct) {
        bool isq = (ct >= 4);
        float b = isq ? b2[(ct - 4) * 16 + lr] : 0.f;
        ushort* dstp = isq ? q : p;
        int col = (isq ? (ct - 4) : ct) * 16 + lr;
#pragma unroll
        for (int mr = 0; mr < MREP; ++mr) {
#pragma unroll
            for (int j = 0; j < 4; ++j) {
                int r = rowbase + mr * 16 + kg * 4 + j;
                if (r < n) dstp[(size_t)r * 64 + col] = f2bf(acc[mr][ct][j] + b);
            }
        }
    }
}

// ---------------- final: out = log_softmax(mean_p + q) ----------------
__global__ void final_ls_kernel(const float* __restrict__ meanp, const ushort* __restrict__ q,
                                float* __restrict__ out, int n) {
    int node = blockIdx.x * 4 + (threadIdx.x >> 6);
    if (node >= n) return;
    int lane = threadIdx.x & 63;
    float v = meanp[(size_t)node * 64 + lane] + bf1(q[(size_t)node * 64 + lane]);
    float m = v;
#pragma unroll
    for (int d = 32; d >= 1; d >>= 1) m = fmaxf(m, __shfl_xor(m, d, 64));
    float ex = __expf(v - m);
    float s = ex;
#pragma unroll
    for (int d = 32; d >= 1; d >>= 1) s += __shfl_xor(s, d, 64);
    out[(size_t)node * 64 + lane] = v - m - logf(s);
}

extern "C" void kernel_launch(void* const* d_in, const int* in_sizes, int n_in,
                              void* d_out, int out_size, void* d_ws, size_t ws_size,
                              hipStream_t stream) {
    const float* x   = (const float*)d_in[0];
    const int*   ei  = (const int*)d_in[1];
    const float* W0l = (const float*)d_in[2];
    const float* b0  = (const float*)d_in[3];
    const float* W0r = (const float*)d_in[4];
    const float* W1l = (const float*)d_in[5];
    const float* b1  = (const float*)d_in[6];
    const float* W1r = (const float*)d_in[7];
    const float* W2l = (const float*)d_in[8];
    const float* b2  = (const float*)d_in[9];
    const float* W2r = (const float*)d_in[10];

    int n = in_sizes[0] / N_FEAT;       // 100000
    int E = in_sizes[1] / 2;            // 1600000
    const int* srcv = ei;
    const int* dstv = ei + E;
    int NB = (n + 255) >> 8;            // coarse buckets (width 256 nodes)

    // workspace layout
    char* ws = (char*)d_ws;
    int* off     = (int*)ws;                 // n+1
    int* csr     = off + (n + 1);            // E
    int* btot    = csr + E;                  // NB
    int* bbase   = btot + NBMAX;             // NB+1
    int* gcursor = bbase + NBMAX + 1;        // NB
    size_t intbytes = ((size_t)(n + 1) + E + 3 * NBMAX + 1) * sizeof(int);
    intbytes = (intbytes + 255) & ~(size_t)255;
    ushort* xbf   = (ushort*)(ws + intbytes);       // n*128 bf16
    ushort* meanb = xbf + (size_t)n * N_FEAT;       // n*128  (also: bucketArr, p3|q3)
    ushort* hA    = meanb + (size_t)n * N_FEAT;     // n*128  (also: meanp f32 [n][64])
    ushort* hB    = hA + (size_t)n * N_FEAT;        // n*128
    ushort* wcat0 = hB + (size_t)n * N_FEAT;        // 128*256
    ushort* wcat1 = wcat0 + 128 * 256;              // 128*256
    ushort* wcat3 = wcat1 + 128 * 256;              // 128*128

    uint* bucketArr = (uint*)meanb;                 // E * 4B, used only during CSR build
    ushort* p3 = meanb;                             // n*64 bf16
    ushort* q3 = meanb + (size_t)n * 64;            // n*64 bf16
    float* meanp = (float*)hA;                      // n*64 f32

    int ebGrid = (E + SCHUNK - 1) / SCHUNK;

    // ---- build CSR (bucketed counting sort, packed entries) ----
    hipMemsetAsync(btot, 0, (size_t)NBMAX * sizeof(int), stream);
    bucket_hist_kernel<<<ebGrid, 256, 0, stream>>>(dstv, btot, E, NB);
    bucket_scan_kernel<<<1, 512, 0, stream>>>(btot, bbase, gcursor, NB, off, n);
    bucket_scatter_kernel<<<ebGrid, 256, 0, stream>>>(srcv, dstv, gcursor, bucketArr, E, NB);
    bucket_build_kernel<<<NB, 256, 0, stream>>>(bucketArr, bbase, off, csr, n);

    // ---- convert x and weights to bf16 ----
    int total8 = n * N_FEAT / 8;
    f32_to_bf16_kernel<<<(total8 + 255) / 256, 256, 0, stream>>>(x, (uint4*)xbf, total8);
    wcat_kernel<<<(128 * 64 + 255) / 256, 256, 0, stream>>>(W0l, W0r, wcat0, 128);
    wcat_kernel<<<(128 * 64 + 255) / 256, 256, 0, stream>>>(W1l, W1r, wcat1, 128);
    wcat3_kernel<<<(128 * 32 + 255) / 256, 256, 0, stream>>>(W2l, W2r, wcat3);

    int aggGrid = (n + 3) / 4;
    int gemmGrid = (n + 127) / 128;

    // ---- layer 1 ----
    aggregate128_kernel<<<aggGrid, 256, 0, stream>>>((const uint4*)xbf, off, csr, (uint4*)meanb, n);
    sage_mfma_kernel<8><<<gemmGrid, 256, 0, stream>>>(meanb, xbf, wcat0, b0, hA, n);
    // ---- layer 2 ----
    aggregate128_kernel<<<aggGrid, 256, 0, stream>>>((const uint4*)hA, off, csr, (uint4*)meanb, n);
    sage_mfma_kernel<8><<<gemmGrid, 256, 0, stream>>>(meanb, hA, wcat1, b1, hB, n);
    // ---- layer 3: transform first, then aggregate 64-wide ----
    gemm3_kernel<<<gemmGrid, 256, 0, stream>>>(hB, wcat3, b2, p3, q3, n);
    aggregate64_kernel<<<aggGrid, 256, 0, stream>>>((const uint4*)p3, off, csr, (float4*)meanp, n);
    final_ls_kernel<<<aggGrid, 256, 0, stream>>>(meanp, q3, (float*)d_out, n);
}

// Round 5
// 360.058 us; speedup vs baseline: 2.4969x; 1.2030x over previous
//
#include <hip/hip_runtime.h>
#include <hip/hip_bf16.h>

// ---------------------------------------------------------------------------
// GraphSAGE 3-layer forward, bf16-MFMA + bucketed CSR build.
//   layer: out = mean_agg(h) @ Wl^T + b + h @ Wr^T   (ReLU between layers)
// GEMMs: swapped-operand MFMA (output-row lane-local -> packed stores),
// fragment-major W (coalesced 1KB fragment loads), fully hoisted A fragments
// (max loads in flight). CSR via bucketed counting sort. Layer 3 transforms
// before aggregating (mean is linear), then fused add + log_softmax.
// ---------------------------------------------------------------------------

#define N_FEAT 128
#define NBMAX 512          // max coarse buckets (node width 256)
#define SCHUNK 2048        // edges per block in hist/scatter passes

typedef __attribute__((ext_vector_type(8))) short short8;   // 8 bf16 = 4 VGPRs
typedef __attribute__((ext_vector_type(4))) float f32x4;

__device__ __forceinline__ ushort f2bf(float f) {
    union { float f; uint u; } v; v.f = f;
    uint u = v.u;
    return (ushort)((u + 0x7fffu + ((u >> 16) & 1u)) >> 16);   // RNE
}
__device__ __forceinline__ uint pack2bf(float x, float y) {
    return (uint)f2bf(x) | ((uint)f2bf(y) << 16);
}
__device__ __forceinline__ float bflo(uint v) {
    union { uint u; float f; } c; c.u = v << 16; return c.f;
}
__device__ __forceinline__ float bfhi(uint v) {
    union { uint u; float f; } c; c.u = v & 0xffff0000u; return c.f;
}
__device__ __forceinline__ float bf1(ushort v) {
    union { uint u; float f; } c; c.u = ((uint)v) << 16; return c.f;
}

// ---------------- block inclusive scan helper ----------------
__device__ __forceinline__ int block_inclusive_scan(int v, int* lds_waves, int tid, int nthreads) {
    int lane = tid & 63;
    int wid  = tid >> 6;
#pragma unroll
    for (int d = 1; d < 64; d <<= 1) {
        int t = __shfl_up(v, d, 64);
        if (lane >= d) v += t;
    }
    if (lane == 63) lds_waves[wid] = v;
    __syncthreads();
    if (wid == 0) {
        int nw = nthreads >> 6;
        int s = (lane < nw) ? lds_waves[lane] : 0;
#pragma unroll
        for (int d = 1; d < 16; d <<= 1) {
            int t = __shfl_up(s, d, 64);
            if (lane >= d) s += t;
        }
        if (lane < nw) lds_waves[lane] = s;
    }
    __syncthreads();
    int add = (wid > 0) ? lds_waves[wid - 1] : 0;
    return v + add;
}

// ---------------- pass A: coarse-bucket histogram ----------------
__global__ void bucket_hist_kernel(const int* __restrict__ dst, int* __restrict__ btot,
                                   int E, int NB) {
    __shared__ int cnt[NBMAX];
    int tid = threadIdx.x;
    for (int i = tid; i < NB; i += 256) cnt[i] = 0;
    __syncthreads();
    int idx = blockIdx.x * SCHUNK + tid * 8;
    if (idx < E) {
        int4 d0 = *(const int4*)&dst[idx];
        int4 d1 = *(const int4*)&dst[idx + 4];
        atomicAdd(&cnt[d0.x >> 8], 1); atomicAdd(&cnt[d0.y >> 8], 1);
        atomicAdd(&cnt[d0.z >> 8], 1); atomicAdd(&cnt[d0.w >> 8], 1);
        atomicAdd(&cnt[d1.x >> 8], 1); atomicAdd(&cnt[d1.y >> 8], 1);
        atomicAdd(&cnt[d1.z >> 8], 1); atomicAdd(&cnt[d1.w >> 8], 1);
    }
    __syncthreads();
    for (int i = tid; i < NB; i += 256)
        if (cnt[i]) atomicAdd(&btot[i], cnt[i]);
}

// ---------------- scan bucket totals -> bases, init cursors ----------------
__global__ void bucket_scan_kernel(const int* __restrict__ btot, int* __restrict__ bbase,
                                   int* __restrict__ gcursor, int NB, int* __restrict__ off, int n) {
    __shared__ int lds[8];
    int t = threadIdx.x;
    int v = (t < NB) ? btot[t] : 0;
    int incl = block_inclusive_scan(v, lds, t, 512);
    if (t < NB) { bbase[t] = incl - v; gcursor[t] = incl - v; }
    if (t == NB - 1) { bbase[NB] = incl; off[n] = incl; }
}

// ---------------- pass B: scatter packed (dloc<<24|src) into buckets --------
__global__ void bucket_scatter_kernel(const int* __restrict__ src, const int* __restrict__ dst,
                                      int* __restrict__ gcursor, uint* __restrict__ bucketArr,
                                      int E, int NB) {
    __shared__ int cnt[NBMAX];
    __shared__ int gbase[NBMAX];
    int tid = threadIdx.x;
    for (int i = tid; i < NB; i += 256) cnt[i] = 0;
    __syncthreads();
    int idx = blockIdx.x * SCHUNK + tid * 8;
    int s[8], d[8], r[8];
    bool valid = (idx < E);
    if (valid) {
        int4 s0 = *(const int4*)&src[idx];
        int4 s1 = *(const int4*)&src[idx + 4];
        int4 d0 = *(const int4*)&dst[idx];
        int4 d1 = *(const int4*)&dst[idx + 4];
        s[0]=s0.x; s[1]=s0.y; s[2]=s0.z; s[3]=s0.w;
        s[4]=s1.x; s[5]=s1.y; s[6]=s1.z; s[7]=s1.w;
        d[0]=d0.x; d[1]=d0.y; d[2]=d0.z; d[3]=d0.w;
        d[4]=d1.x; d[5]=d1.y; d[6]=d1.z; d[7]=d1.w;
#pragma unroll
        for (int j = 0; j < 8; ++j) r[j] = atomicAdd(&cnt[d[j] >> 8], 1);
    }
    __syncthreads();
    for (int i = tid; i < NB; i += 256)
        if (cnt[i]) gbase[i] = atomicAdd(&gcursor[i], cnt[i]);
    __syncthreads();
    if (valid) {
#pragma unroll
        for (int j = 0; j < 8; ++j) {
            int b = d[j] >> 8;
            uint p = ((uint)(d[j] & 255) << 24) | (uint)s[j];
            bucketArr[(size_t)gbase[b] + r[j]] = p;
        }
    }
}

// ---------------- pass C: per-bucket CSR build (off + csr) ----------------
__global__ void bucket_build_kernel(const uint* __restrict__ bucketArr, const int* __restrict__ bbase,
                                    int* __restrict__ off, int* __restrict__ csr, int n) {
    __shared__ int cnt[256];
    __shared__ int lds[4];
    int b = blockIdx.x, tid = threadIdx.x;
    int ebase = bbase[b], eend = bbase[b + 1];
    cnt[tid] = 0;
    __syncthreads();
    for (int i = ebase + tid; i < eend; i += 256) {
        uint p = bucketArr[i];
        atomicAdd(&cnt[p >> 24], 1);
    }
    __syncthreads();
    int v = cnt[tid];
    int incl = block_inclusive_scan(v, lds, tid, 256);
    int excl = incl - v;
    int node = b * 256 + tid;
    if (node < n) off[node] = ebase + excl;
    __syncthreads();
    cnt[tid] = excl;
    __syncthreads();
    for (int i = ebase + tid; i < eend; i += 256) {
        uint p = bucketArr[i];
        int pos = ebase + atomicAdd(&cnt[p >> 24], 1);
        csr[pos] = (int)(p & 0xFFFFFFu);
    }
}

// ---------------- fp32 -> bf16 conversions ----------------
__global__ void f32_to_bf16_kernel(const float* __restrict__ in, uint4* __restrict__ out, int total8) {
    int i = blockIdx.x * 256 + threadIdx.x;
    if (i >= total8) return;
    const float4* in4 = (const float4*)in;
    float4 a = in4[i * 2], b = in4[i * 2 + 1];
    uint4 o;
    o.x = pack2bf(a.x, a.y);
    o.y = pack2bf(a.z, a.w);
    o.z = pack2bf(b.x, b.y);
    o.w = pack2bf(b.z, b.w);
    out[i] = o;
}

// ---------------- fragment-major W for layers 1-2 ----------------
// Wf[(ct*8+ks)*64 + lane] (8 bf16 each): lane -> (lr=lane&15, kg=lane>>4);
// source row = ct*16+lr of Wl (ks<4) or Wr (ks>=4), k = (ks&3)*32 + kg*8.
__global__ void wcatF_kernel(const float* __restrict__ Wl, const float* __restrict__ Wr,
                             ushort* __restrict__ out) {
    int tid = blockIdx.x * 256 + threadIdx.x;     // over 8*8*64
    if (tid >= 8 * 8 * 64) return;
    int lane = tid & 63, ks = (tid >> 6) & 7, ct = tid >> 9;
    int lr = lane & 15, kg = lane >> 4;
    int row = ct * 16 + lr, k = (ks & 3) * 32 + kg * 8;
    const float* s = (ks < 4) ? &Wl[(size_t)row * 128 + k] : &Wr[(size_t)row * 128 + k];
    float4 v0 = *(const float4*)s;
    float4 v1 = *(const float4*)(s + 4);
    uint4 o;
    o.x = pack2bf(v0.x, v0.y); o.y = pack2bf(v0.z, v0.w);
    o.z = pack2bf(v1.x, v1.y); o.w = pack2bf(v1.z, v1.w);
    *(uint4*)&out[(size_t)tid * 8] = o;
}

// ---------------- fragment-major W for layer 3 ----------------
// Stacked [W2l ; W2r] (128 rows). Wf3[(ct*4+ks)*64 + lane]; row = ct*16+lr,
// k = ks*32 + kg*8; rows 0-63 from W2l (->p), 64-127 from W2r (->q).
__global__ void wcat3F_kernel(const float* __restrict__ W2l, const float* __restrict__ W2r,
                              ushort* __restrict__ out) {
    int tid = blockIdx.x * 256 + threadIdx.x;     // over 8*4*64
    if (tid >= 8 * 4 * 64) return;
    int lane = tid & 63, ks = (tid >> 6) & 3, ct = tid >> 8;
    int lr = lane & 15, kg = lane >> 4;
    int row = ct * 16 + lr, k = ks * 32 + kg * 8;
    const float* s = (row < 64) ? &W2l[(size_t)row * 128 + k] : &W2r[(size_t)(row - 64) * 128 + k];
    float4 v0 = *(const float4*)s;
    float4 v1 = *(const float4*)(s + 4);
    uint4 o;
    o.x = pack2bf(v0.x, v0.y); o.y = pack2bf(v0.z, v0.w);
    o.z = pack2bf(v1.x, v1.y); o.w = pack2bf(v1.z, v1.w);
    *(uint4*)&out[(size_t)tid * 8] = o;
}

// ---------------- mean aggregation (bf16 128-wide), 16 B/lane gathers --------
__global__ void aggregate128_kernel(const uint4* __restrict__ x4, const int* __restrict__ off,
                                    const int* __restrict__ csr, uint4* __restrict__ meanout, int n) {
    int node = blockIdx.x * 4 + (threadIdx.x >> 6);
    if (node >= n) return;
    int lane = threadIdx.x & 63;
    int g = lane >> 4, lr = lane & 15;
    int s = off[node], e = off[node + 1];
    float acc[8];
#pragma unroll
    for (int j = 0; j < 8; ++j) acc[j] = 0.f;

    int i = s + g;
    for (; i + 4 < e; i += 8) {
        int s0 = csr[i], s1 = csr[i + 4];
        uint4 v0 = x4[(size_t)s0 * 16 + lr];
        uint4 v1 = x4[(size_t)s1 * 16 + lr];
        acc[0] += bflo(v0.x) + bflo(v1.x);
        acc[1] += bfhi(v0.x) + bfhi(v1.x);
        acc[2] += bflo(v0.y) + bflo(v1.y);
        acc[3] += bfhi(v0.y) + bfhi(v1.y);
        acc[4] += bflo(v0.z) + bflo(v1.z);
        acc[5] += bfhi(v0.z) + bfhi(v1.z);
        acc[6] += bflo(v0.w) + bflo(v1.w);
        acc[7] += bfhi(v0.w) + bfhi(v1.w);
    }
    if (i < e) {
        uint4 v = x4[(size_t)csr[i] * 16 + lr];
        acc[0] += bflo(v.x); acc[1] += bfhi(v.x);
        acc[2] += bflo(v.y); acc[3] += bfhi(v.y);
        acc[4] += bflo(v.z); acc[5] += bfhi(v.z);
        acc[6] += bflo(v.w); acc[7] += bfhi(v.w);
    }
#pragma unroll
    for (int j = 0; j < 8; ++j) {
        acc[j] += __shfl_xor(acc[j], 16, 64);
        acc[j] += __shfl_xor(acc[j], 32, 64);
    }
    if (g == 0) {
        float inv = (e > s) ? 1.0f / (float)(e - s) : 0.f;
        uint4 o;
        o.x = pack2bf(acc[0] * inv, acc[1] * inv);
        o.y = pack2bf(acc[2] * inv, acc[3] * inv);
        o.z = pack2bf(acc[4] * inv, acc[5] * inv);
        o.w = pack2bf(acc[6] * inv, acc[7] * inv);
        meanout[(size_t)node * 16 + lr] = o;
    }
}

// ---------------- mean aggregation (bf16 64-wide -> f32), layer 3 ------------
__global__ void aggregate64_kernel(const uint4* __restrict__ p4, const int* __restrict__ off,
                                   const int* __restrict__ csr, float4* __restrict__ meanout, int n) {
    int node = blockIdx.x * 4 + (threadIdx.x >> 6);
    if (node >= n) return;
    int lane = threadIdx.x & 63;
    int g = lane >> 3, lr = lane & 7;
    int s = off[node], e = off[node + 1];
    float acc[8];
#pragma unroll
    for (int j = 0; j < 8; ++j) acc[j] = 0.f;

    int i = s + g;
    for (; i + 8 < e; i += 16) {
        int s0 = csr[i], s1 = csr[i + 8];
        uint4 v0 = p4[(size_t)s0 * 8 + lr];
        uint4 v1 = p4[(size_t)s1 * 8 + lr];
        acc[0] += bflo(v0.x) + bflo(v1.x);
        acc[1] += bfhi(v0.x) + bfhi(v1.x);
        acc[2] += bflo(v0.y) + bflo(v1.y);
        acc[3] += bfhi(v0.y) + bfhi(v1.y);
        acc[4] += bflo(v0.z) + bflo(v1.z);
        acc[5] += bfhi(v0.z) + bfhi(v1.z);
        acc[6] += bflo(v0.w) + bflo(v1.w);
        acc[7] += bfhi(v0.w) + bfhi(v1.w);
    }
    if (i < e) {
        uint4 v = p4[(size_t)csr[i] * 8 + lr];
        acc[0] += bflo(v.x); acc[1] += bfhi(v.x);
        acc[2] += bflo(v.y); acc[3] += bfhi(v.y);
        acc[4] += bflo(v.z); acc[5] += bfhi(v.z);
        acc[6] += bflo(v.w); acc[7] += bfhi(v.w);
    }
#pragma unroll
    for (int j = 0; j < 8; ++j) {
        acc[j] += __shfl_xor(acc[j], 8, 64);
        acc[j] += __shfl_xor(acc[j], 16, 64);
        acc[j] += __shfl_xor(acc[j], 32, 64);
    }
    if (g == 0) {
        float inv = (e > s) ? 1.0f / (float)(e - s) : 0.f;
        float4 o0, o1;
        o0.x = acc[0] * inv; o0.y = acc[1] * inv; o0.z = acc[2] * inv; o0.w = acc[3] * inv;
        o1.x = acc[4] * inv; o1.y = acc[5] * inv; o1.z = acc[6] * inv; o1.w = acc[7] * inv;
        meanout[(size_t)node * 16 + lr * 2]     = o0;
        meanout[(size_t)node * 16 + lr * 2 + 1] = o1;
    }
}

// ---------------- MFMA dual GEMM (layers 1-2), swapped operands --------------
// out[m][o] = sum_k [mean|h][m][k] * W[o][k] + b[o], ReLU, bf16 store.
// K=256 (mean 0-127, h 128-255), HO=128. Wave: 32 rows; block: 128 rows.
// Swapped mfma(Wfrag, Afrag): lane holds row lr (per mr), cols ct*16+kg*4+0..3.
__global__ __launch_bounds__(256)
void sage_mfma2_kernel(const ushort* __restrict__ Amean, const ushort* __restrict__ Ah,
                       const ushort* __restrict__ Wf, const float* __restrict__ bias,
                       ushort* __restrict__ out, int n) {
    int wid = threadIdx.x >> 6, lane = threadIdx.x & 63;
    int rowbase = blockIdx.x * 128 + wid * 32;
    int lr = lane & 15, kg = lane >> 4;

    // hoist ALL A fragments: a[mr][ks], 16 independent loads in flight
    short8 a[2][8];
#pragma unroll
    for (int mr = 0; mr < 2; ++mr) {
        int r = rowbase + mr * 16 + lr;
        if (r > n - 1) r = n - 1;
#pragma unroll
        for (int ks = 0; ks < 8; ++ks) {
            const ushort* Asrc = (ks < 4) ? Amean : Ah;
            int koff = (ks & 3) * 32 + kg * 8;
            a[mr][ks] = *(const short8*)&Asrc[(size_t)r * 128 + koff];
        }
    }

#pragma unroll
    for (int half = 0; half < 2; ++half) {
        f32x4 acc[2][4];
#pragma unroll
        for (int mr = 0; mr < 2; ++mr)
#pragma unroll
            for (int c = 0; c < 4; ++c)
#pragma unroll
                for (int j = 0; j < 4; ++j) acc[mr][c][j] = 0.f;

#pragma unroll
        for (int c = 0; c < 4; ++c) {
            int ct = half * 4 + c;
            short8 w[8];
#pragma unroll
            for (int ks = 0; ks < 8; ++ks)
                w[ks] = *(const short8*)&Wf[(size_t)((ct * 8 + ks) * 64 + lane) * 8];
#pragma unroll
            for (int ks = 0; ks < 8; ++ks)
#pragma unroll
                for (int mr = 0; mr < 2; ++mr)
                    acc[mr][c] = __builtin_amdgcn_mfma_f32_16x16x32_bf16(w[ks], a[mr][ks], acc[mr][c], 0, 0, 0);
        }

        // epilogue: lane writes rows lr (+mr*16), cols ct*16 + kg*4 + 0..3
#pragma unroll
        for (int mr = 0; mr < 2; ++mr) {
            int r = rowbase + mr * 16 + lr;
            if (r < n) {
#pragma unroll
                for (int c = 0; c < 4; ++c) {
                    int col = (half * 4 + c) * 16 + kg * 4;
                    float4 b4 = *(const float4*)&bias[col];
                    float v0 = fmaxf(acc[mr][c][0] + b4.x, 0.f);
                    float v1 = fmaxf(acc[mr][c][1] + b4.y, 0.f);
                    float v2 = fmaxf(acc[mr][c][2] + b4.z, 0.f);
                    float v3 = fmaxf(acc[mr][c][3] + b4.w, 0.f);
                    uint2 o;
                    o.x = pack2bf(v0, v1);
                    o.y = pack2bf(v2, v3);
                    *(uint2*)&out[(size_t)r * 128 + col] = o;
                }
            }
        }
    }
}

// ---------------- layer-3 transform GEMM: p = h@W2l^T, q = h@W2r^T + b2 ------
// Wf3 fragment-major of stacked [W2l;W2r]; K=128; ct 0-3 -> p, 4-7 -> q.
__global__ __launch_bounds__(256)
void gemm3_kernel(const ushort* __restrict__ Ah, const ushort* __restrict__ Wf3,
                  const float* __restrict__ b2, ushort* __restrict__ p,
                  ushort* __restrict__ q, int n) {
    int wid = threadIdx.x >> 6, lane = threadIdx.x & 63;
    int rowbase = blockIdx.x * 128 + wid * 32;
    int lr = lane & 15, kg = lane >> 4;

    short8 a[2][4];
#pragma unroll
    for (int mr = 0; mr < 2; ++mr) {
        int r = rowbase + mr * 16 + lr;
        if (r > n - 1) r = n - 1;
#pragma unroll
        for (int ks = 0; ks < 4; ++ks)
            a[mr][ks] = *(const short8*)&Ah[(size_t)r * 128 + ks * 32 + kg * 8];
    }

    f32x4 acc[2][8];
#pragma unroll
    for (int mr = 0; mr < 2; ++mr)
#pragma unroll
        for (int ct = 0; ct < 8; ++ct)
#pragma unroll
            for (int j = 0; j < 4; ++j) acc[mr][ct][j] = 0.f;

#pragma unroll
    for (int ct = 0; ct < 8; ++ct) {
        short8 w[4];
#pragma unroll
        for (int ks = 0; ks < 4; ++ks)
            w[ks] = *(const short8*)&Wf3[(size_t)((ct * 4 + ks) * 64 + lane) * 8];
#pragma unroll
        for (int ks = 0; ks < 4; ++ks)
#pragma unroll
            for (int mr = 0; mr < 2; ++mr)
                acc[mr][ct] = __builtin_amdgcn_mfma_f32_16x16x32_bf16(w[ks], a[mr][ks], acc[mr][ct], 0, 0, 0);
    }

#pragma unroll
    for (int mr = 0; mr < 2; ++mr) {
        int r = rowbase + mr * 16 + lr;
        if (r >= n) continue;
#pragma unroll
        for (int ct = 0; ct < 8; ++ct) {
            bool isq = (ct >= 4);
            int col = (isq ? (ct - 4) : ct) * 16 + kg * 4;
            float b0 = 0.f, b1 = 0.f, b2v = 0.f, b3 = 0.f;
            if (isq) {
                float4 b4 = *(const float4*)&b2[col];
                b0 = b4.x; b1 = b4.y; b2v = b4.z; b3 = b4.w;
            }
            uint2 o;
            o.x = pack2bf(acc[mr][ct][0] + b0, acc[mr][ct][1] + b1);
            o.y = pack2bf(acc[mr][ct][2] + b2v, acc[mr][ct][3] + b3);
            ushort* dstp = isq ? q : p;
            *(uint2*)&dstp[(size_t)r * 64 + col] = o;
        }
    }
}

// ---------------- final: out = log_softmax(mean_p + q) ----------------
__global__ void final_ls_kernel(const float* __restrict__ meanp, const ushort* __restrict__ q,
                                float* __restrict__ out, int n) {
    int node = blockIdx.x * 4 + (threadIdx.x >> 6);
    if (node >= n) return;
    int lane = threadIdx.x & 63;
    float v = meanp[(size_t)node * 64 + lane] + bf1(q[(size_t)node * 64 + lane]);
    float m = v;
#pragma unroll
    for (int d = 32; d >= 1; d >>= 1) m = fmaxf(m, __shfl_xor(m, d, 64));
    float ex = __expf(v - m);
    float s = ex;
#pragma unroll
    for (int d = 32; d >= 1; d >>= 1) s += __shfl_xor(s, d, 64);
    out[(size_t)node * 64 + lane] = v - m - logf(s);
}

extern "C" void kernel_launch(void* const* d_in, const int* in_sizes, int n_in,
                              void* d_out, int out_size, void* d_ws, size_t ws_size,
                              hipStream_t stream) {
    const float* x   = (const float*)d_in[0];
    const int*   ei  = (const int*)d_in[1];
    const float* W0l = (const float*)d_in[2];
    const float* b0  = (const float*)d_in[3];
    const float* W0r = (const float*)d_in[4];
    const float* W1l = (const float*)d_in[5];
    const float* b1  = (const float*)d_in[6];
    const float* W1r = (const float*)d_in[7];
    const float* W2l = (const float*)d_in[8];
    const float* b2  = (const float*)d_in[9];
    const float* W2r = (const float*)d_in[10];

    int n = in_sizes[0] / N_FEAT;       // 100000
    int E = in_sizes[1] / 2;            // 1600000
    const int* srcv = ei;
    const int* dstv = ei + E;
    int NB = (n + 255) >> 8;            // coarse buckets (width 256 nodes)

    // workspace layout
    char* ws = (char*)d_ws;
    int* off     = (int*)ws;                 // n+1
    int* csr     = off + (n + 1);            // E
    int* btot    = csr + E;                  // NB
    int* bbase   = btot + NBMAX;             // NB+1
    int* gcursor = bbase + NBMAX + 1;        // NB
    size_t intbytes = ((size_t)(n + 1) + E + 3 * NBMAX + 1) * sizeof(int);
    intbytes = (intbytes + 255) & ~(size_t)255;
    ushort* xbf   = (ushort*)(ws + intbytes);       // n*128 bf16
    ushort* meanb = xbf + (size_t)n * N_FEAT;       // n*128  (also: bucketArr, p3|q3)
    ushort* hA    = meanb + (size_t)n * N_FEAT;     // n*128  (also: meanp f32 [n][64])
    ushort* hB    = hA + (size_t)n * N_FEAT;        // n*128
    ushort* wcat0 = hB + (size_t)n * N_FEAT;        // 8*8*64*8 = 32768
    ushort* wcat1 = wcat0 + 32768;                  // 32768
    ushort* wcat3 = wcat1 + 32768;                  // 8*4*64*8 = 16384

    uint* bucketArr = (uint*)meanb;                 // E * 4B, used only during CSR build
    ushort* p3 = meanb;                             // n*64 bf16
    ushort* q3 = meanb + (size_t)n * 64;            // n*64 bf16
    float* meanp = (float*)hA;                      // n*64 f32

    int ebGrid = (E + SCHUNK - 1) / SCHUNK;

    // ---- build CSR (bucketed counting sort, packed entries) ----
    hipMemsetAsync(btot, 0, (size_t)NBMAX * sizeof(int), stream);
    bucket_hist_kernel<<<ebGrid, 256, 0, stream>>>(dstv, btot, E, NB);
    bucket_scan_kernel<<<1, 512, 0, stream>>>(btot, bbase, gcursor, NB, off, n);
    bucket_scatter_kernel<<<ebGrid, 256, 0, stream>>>(srcv, dstv, gcursor, bucketArr, E, NB);
    bucket_build_kernel<<<NB, 256, 0, stream>>>(bucketArr, bbase, off, csr, n);

    // ---- convert x and weights to bf16 (fragment-major W) ----
    int total8 = n * N_FEAT / 8;
    f32_to_bf16_kernel<<<(total8 + 255) / 256, 256, 0, stream>>>(x, (uint4*)xbf, total8);
    wcatF_kernel<<<16, 256, 0, stream>>>(W0l, W0r, wcat0);
    wcatF_kernel<<<16, 256, 0, stream>>>(W1l, W1r, wcat1);
    wcat3F_kernel<<<8, 256, 0, stream>>>(W2l, W2r, wcat3);

    int aggGrid = (n + 3) / 4;
    int gemmGrid = (n + 127) / 128;

    // ---- layer 1 ----
    aggregate128_kernel<<<aggGrid, 256, 0, stream>>>((const uint4*)xbf, off, csr, (uint4*)meanb, n);
    sage_mfma2_kernel<<<gemmGrid, 256, 0, stream>>>(meanb, xbf, wcat0, b0, hA, n);
    // ---- layer 2 ----
    aggregate128_kernel<<<aggGrid, 256, 0, stream>>>((const uint4*)hA, off, csr, (uint4*)meanb, n);
    sage_mfma2_kernel<<<gemmGrid, 256, 0, stream>>>(meanb, hA, wcat1, b1, hB, n);
    // ---- layer 3: transform first, then aggregate 64-wide ----
    gemm3_kernel<<<gemmGrid, 256, 0, stream>>>(hB, wcat3, b2, p3, q3, n);
    aggregate64_kernel<<<aggGrid, 256, 0, stream>>>((const uint4*)p3, off, csr, (float4*)meanp, n);
    final_ls_kernel<<<aggGrid, 256, 0, stream>>>(meanp, q3, (float*)d_out, n);
}

// Round 6
// 336.765 us; speedup vs baseline: 2.6696x; 1.0692x over previous
//
#include <hip/hip_runtime.h>
#include <hip/hip_bf16.h>

// ---------------------------------------------------------------------------
// GraphSAGE 3-layer forward, bf16-MFMA + bucketed CSR build.
//   layer: out = mean_agg(h) @ Wl^T + b + h @ Wr^T   (ReLU between layers)
// GEMMs: swapped-operand MFMA (output-row lane-local -> packed stores),
// fragment-major W (coalesced fragment loads), hoisted A fragments.
// Aggregation: one 16-lane group per node, 4-deep unrolled gathers.
// Layer 3: transform-before-aggregate, then fused mean+add+log_softmax.
// ---------------------------------------------------------------------------

#define N_FEAT 128
#define NBMAX 512          // max coarse buckets (node width 256)
#define SCHUNK 2048        // edges per block in hist/scatter passes

typedef __attribute__((ext_vector_type(8))) short short8;   // 8 bf16 = 4 VGPRs
typedef __attribute__((ext_vector_type(4))) float f32x4;

__device__ __forceinline__ ushort f2bf(float f) {
    union { float f; uint u; } v; v.f = f;
    uint u = v.u;
    return (ushort)((u + 0x7fffu + ((u >> 16) & 1u)) >> 16);   // RNE
}
__device__ __forceinline__ uint pack2bf(float x, float y) {
    return (uint)f2bf(x) | ((uint)f2bf(y) << 16);
}
__device__ __forceinline__ float bflo(uint v) {
    union { uint u; float f; } c; c.u = v << 16; return c.f;
}
__device__ __forceinline__ float bfhi(uint v) {
    union { uint u; float f; } c; c.u = v & 0xffff0000u; return c.f;
}

__device__ __forceinline__ void acc8(float* acc, uint4 v) {
    acc[0] += bflo(v.x); acc[1] += bfhi(v.x);
    acc[2] += bflo(v.y); acc[3] += bfhi(v.y);
    acc[4] += bflo(v.z); acc[5] += bfhi(v.z);
    acc[6] += bflo(v.w); acc[7] += bfhi(v.w);
}

// ---------------- block inclusive scan helper ----------------
__device__ __forceinline__ int block_inclusive_scan(int v, int* lds_waves, int tid, int nthreads) {
    int lane = tid & 63;
    int wid  = tid >> 6;
#pragma unroll
    for (int d = 1; d < 64; d <<= 1) {
        int t = __shfl_up(v, d, 64);
        if (lane >= d) v += t;
    }
    if (lane == 63) lds_waves[wid] = v;
    __syncthreads();
    if (wid == 0) {
        int nw = nthreads >> 6;
        int s = (lane < nw) ? lds_waves[lane] : 0;
#pragma unroll
        for (int d = 1; d < 16; d <<= 1) {
            int t = __shfl_up(s, d, 64);
            if (lane >= d) s += t;
        }
        if (lane < nw) lds_waves[lane] = s;
    }
    __syncthreads();
    int add = (wid > 0) ? lds_waves[wid - 1] : 0;
    return v + add;
}

// ---------------- pass A: coarse-bucket histogram ----------------
__global__ void bucket_hist_kernel(const int* __restrict__ dst, int* __restrict__ btot,
                                   int E, int NB) {
    __shared__ int cnt[NBMAX];
    int tid = threadIdx.x;
    for (int i = tid; i < NB; i += 256) cnt[i] = 0;
    __syncthreads();
    int idx = blockIdx.x * SCHUNK + tid * 8;
    if (idx < E) {
        int4 d0 = *(const int4*)&dst[idx];
        int4 d1 = *(const int4*)&dst[idx + 4];
        atomicAdd(&cnt[d0.x >> 8], 1); atomicAdd(&cnt[d0.y >> 8], 1);
        atomicAdd(&cnt[d0.z >> 8], 1); atomicAdd(&cnt[d0.w >> 8], 1);
        atomicAdd(&cnt[d1.x >> 8], 1); atomicAdd(&cnt[d1.y >> 8], 1);
        atomicAdd(&cnt[d1.z >> 8], 1); atomicAdd(&cnt[d1.w >> 8], 1);
    }
    __syncthreads();
    for (int i = tid; i < NB; i += 256)
        if (cnt[i]) atomicAdd(&btot[i], cnt[i]);
}

// ---------------- scan bucket totals -> bases, init cursors ----------------
__global__ void bucket_scan_kernel(const int* __restrict__ btot, int* __restrict__ bbase,
                                   int* __restrict__ gcursor, int NB, int* __restrict__ off, int n) {
    __shared__ int lds[8];
    int t = threadIdx.x;
    int v = (t < NB) ? btot[t] : 0;
    int incl = block_inclusive_scan(v, lds, t, 512);
    if (t < NB) { bbase[t] = incl - v; gcursor[t] = incl - v; }
    if (t == NB - 1) { bbase[NB] = incl; off[n] = incl; }
}

// ---------------- pass B: scatter packed (dloc<<24|src) into buckets --------
__global__ void bucket_scatter_kernel(const int* __restrict__ src, const int* __restrict__ dst,
                                      int* __restrict__ gcursor, uint* __restrict__ bucketArr,
                                      int E, int NB) {
    __shared__ int cnt[NBMAX];
    __shared__ int gbase[NBMAX];
    int tid = threadIdx.x;
    for (int i = tid; i < NB; i += 256) cnt[i] = 0;
    __syncthreads();
    int idx = blockIdx.x * SCHUNK + tid * 8;
    int s[8], d[8], r[8];
    bool valid = (idx < E);
    if (valid) {
        int4 s0 = *(const int4*)&src[idx];
        int4 s1 = *(const int4*)&src[idx + 4];
        int4 d0 = *(const int4*)&dst[idx];
        int4 d1 = *(const int4*)&dst[idx + 4];
        s[0]=s0.x; s[1]=s0.y; s[2]=s0.z; s[3]=s0.w;
        s[4]=s1.x; s[5]=s1.y; s[6]=s1.z; s[7]=s1.w;
        d[0]=d0.x; d[1]=d0.y; d[2]=d0.z; d[3]=d0.w;
        d[4]=d1.x; d[5]=d1.y; d[6]=d1.z; d[7]=d1.w;
#pragma unroll
        for (int j = 0; j < 8; ++j) r[j] = atomicAdd(&cnt[d[j] >> 8], 1);
    }
    __syncthreads();
    for (int i = tid; i < NB; i += 256)
        if (cnt[i]) gbase[i] = atomicAdd(&gcursor[i], cnt[i]);
    __syncthreads();
    if (valid) {
#pragma unroll
        for (int j = 0; j < 8; ++j) {
            int b = d[j] >> 8;
            uint p = ((uint)(d[j] & 255) << 24) | (uint)s[j];
            bucketArr[(size_t)gbase[b] + r[j]] = p;
        }
    }
}

// ---------------- pass C: per-bucket CSR build (off + csr) ----------------
__global__ void bucket_build_kernel(const uint* __restrict__ bucketArr, const int* __restrict__ bbase,
                                    int* __restrict__ off, int* __restrict__ csr, int n) {
    __shared__ int cnt[256];
    __shared__ int lds[4];
    int b = blockIdx.x, tid = threadIdx.x;
    int ebase = bbase[b], eend = bbase[b + 1];
    cnt[tid] = 0;
    __syncthreads();
    for (int i = ebase + tid; i < eend; i += 256) {
        uint p = bucketArr[i];
        atomicAdd(&cnt[p >> 24], 1);
    }
    __syncthreads();
    int v = cnt[tid];
    int incl = block_inclusive_scan(v, lds, tid, 256);
    int excl = incl - v;
    int node = b * 256 + tid;
    if (node < n) off[node] = ebase + excl;
    __syncthreads();
    cnt[tid] = excl;
    __syncthreads();
    for (int i = ebase + tid; i < eend; i += 256) {
        uint p = bucketArr[i];
        int pos = ebase + atomicAdd(&cnt[p >> 24], 1);
        csr[pos] = (int)(p & 0xFFFFFFu);
    }
}

// ---------------- fp32 -> bf16 conversions ----------------
__global__ void f32_to_bf16_kernel(const float* __restrict__ in, uint4* __restrict__ out, int total8) {
    int i = blockIdx.x * 256 + threadIdx.x;
    if (i >= total8) return;
    const float4* in4 = (const float4*)in;
    float4 a = in4[i * 2], b = in4[i * 2 + 1];
    uint4 o;
    o.x = pack2bf(a.x, a.y);
    o.y = pack2bf(a.z, a.w);
    o.z = pack2bf(b.x, b.y);
    o.w = pack2bf(b.z, b.w);
    out[i] = o;
}

// ---------------- fragment-major W for layers 1-2 ----------------
// Wf[(ct*8+ks)*64 + lane] (8 bf16 each): lane -> (lr=lane&15, kg=lane>>4);
// source row = ct*16+lr of Wl (ks<4) or Wr (ks>=4), k = (ks&3)*32 + kg*8.
__global__ void wcatF_kernel(const float* __restrict__ Wl, const float* __restrict__ Wr,
                             ushort* __restrict__ out) {
    int tid = blockIdx.x * 256 + threadIdx.x;     // over 8*8*64
    if (tid >= 8 * 8 * 64) return;
    int lane = tid & 63, ks = (tid >> 6) & 7, ct = tid >> 9;
    int lr = lane & 15, kg = lane >> 4;
    int row = ct * 16 + lr, k = (ks & 3) * 32 + kg * 8;
    const float* s = (ks < 4) ? &Wl[(size_t)row * 128 + k] : &Wr[(size_t)row * 128 + k];
    float4 v0 = *(const float4*)s;
    float4 v1 = *(const float4*)(s + 4);
    uint4 o;
    o.x = pack2bf(v0.x, v0.y); o.y = pack2bf(v0.z, v0.w);
    o.z = pack2bf(v1.x, v1.y); o.w = pack2bf(v1.z, v1.w);
    *(uint4*)&out[(size_t)tid * 8] = o;
}

// ---------------- fragment-major W for layer 3 ----------------
// Stacked [W2l ; W2r] (128 rows). Wf3[(ct*4+ks)*64 + lane]; row = ct*16+lr,
// k = ks*32 + kg*8; rows 0-63 from W2l (->p), 64-127 from W2r (->q).
__global__ void wcat3F_kernel(const float* __restrict__ W2l, const float* __restrict__ W2r,
                              ushort* __restrict__ out) {
    int tid = blockIdx.x * 256 + threadIdx.x;     // over 8*4*64
    if (tid >= 8 * 4 * 64) return;
    int lane = tid & 63, ks = (tid >> 6) & 3, ct = tid >> 8;
    int lr = lane & 15, kg = lane >> 4;
    int row = ct * 16 + lr, k = ks * 32 + kg * 8;
    const float* s = (row < 64) ? &W2l[(size_t)row * 128 + k] : &W2r[(size_t)(row - 64) * 128 + k];
    float4 v0 = *(const float4*)s;
    float4 v1 = *(const float4*)(s + 4);
    uint4 o;
    o.x = pack2bf(v0.x, v0.y); o.y = pack2bf(v0.z, v0.w);
    o.z = pack2bf(v1.x, v1.y); o.w = pack2bf(v1.z, v1.w);
    *(uint4*)&out[(size_t)tid * 8] = o;
}

// ---------------- mean aggregation (bf16 128-wide) ----------------
// One 16-lane group per node (4 nodes/wave, 16/block); 4-deep unrolled
// gathers: up to 16 independent 256B row reads in flight per wave.
__global__ void aggregate128_kernel(const uint4* __restrict__ x4, const int* __restrict__ off,
                                    const int* __restrict__ csr, uint4* __restrict__ meanout, int n) {
    int node = blockIdx.x * 16 + (threadIdx.x >> 4);
    if (node >= n) return;
    int lr = threadIdx.x & 15;
    int s = off[node], e = off[node + 1];
    float acc[8];
#pragma unroll
    for (int j = 0; j < 8; ++j) acc[j] = 0.f;

    int i = s;
    for (; i + 3 < e; i += 4) {
        int s0 = csr[i], s1 = csr[i + 1], s2 = csr[i + 2], s3 = csr[i + 3];
        uint4 v0 = x4[(size_t)s0 * 16 + lr];
        uint4 v1 = x4[(size_t)s1 * 16 + lr];
        uint4 v2 = x4[(size_t)s2 * 16 + lr];
        uint4 v3 = x4[(size_t)s3 * 16 + lr];
        acc8(acc, v0); acc8(acc, v1); acc8(acc, v2); acc8(acc, v3);
    }
    for (; i < e; ++i) {
        uint4 v = x4[(size_t)csr[i] * 16 + lr];
        acc8(acc, v);
    }
    float inv = (e > s) ? 1.0f / (float)(e - s) : 0.f;
    uint4 o;
    o.x = pack2bf(acc[0] * inv, acc[1] * inv);
    o.y = pack2bf(acc[2] * inv, acc[3] * inv);
    o.z = pack2bf(acc[4] * inv, acc[5] * inv);
    o.w = pack2bf(acc[6] * inv, acc[7] * inv);
    meanout[(size_t)node * 16 + lr] = o;
}

// ---------------- fused layer-3 tail: out = log_softmax(mean_p + q) ----------
// One 8-lane group per node (8 nodes/wave, 32/block). Each lane holds 8 of
// the 64 classes; intra-group shuffle reduce for max/sum.
__global__ void agg64_ls_kernel(const uint4* __restrict__ p4, const int* __restrict__ off,
                                const int* __restrict__ csr, const uint4* __restrict__ q4,
                                float* __restrict__ out, int n) {
    int node = blockIdx.x * 32 + (threadIdx.x >> 3);
    if (node >= n) return;
    int lr = threadIdx.x & 7;
    int s = off[node], e = off[node + 1];
    float acc[8];
#pragma unroll
    for (int j = 0; j < 8; ++j) acc[j] = 0.f;

    int i = s;
    for (; i + 3 < e; i += 4) {
        int s0 = csr[i], s1 = csr[i + 1], s2 = csr[i + 2], s3 = csr[i + 3];
        uint4 v0 = p4[(size_t)s0 * 8 + lr];
        uint4 v1 = p4[(size_t)s1 * 8 + lr];
        uint4 v2 = p4[(size_t)s2 * 8 + lr];
        uint4 v3 = p4[(size_t)s3 * 8 + lr];
        acc8(acc, v0); acc8(acc, v1); acc8(acc, v2); acc8(acc, v3);
    }
    for (; i < e; ++i) {
        uint4 v = p4[(size_t)csr[i] * 8 + lr];
        acc8(acc, v);
    }
    float inv = (e > s) ? 1.0f / (float)(e - s) : 0.f;

    uint4 qv = q4[(size_t)node * 8 + lr];
    float v[8];
    v[0] = acc[0] * inv + bflo(qv.x); v[1] = acc[1] * inv + bfhi(qv.x);
    v[2] = acc[2] * inv + bflo(qv.y); v[3] = acc[3] * inv + bfhi(qv.y);
    v[4] = acc[4] * inv + bflo(qv.z); v[5] = acc[5] * inv + bfhi(qv.z);
    v[6] = acc[6] * inv + bflo(qv.w); v[7] = acc[7] * inv + bfhi(qv.w);

    float m = v[0];
#pragma unroll
    for (int j = 1; j < 8; ++j) m = fmaxf(m, v[j]);
#pragma unroll
    for (int d = 1; d < 8; d <<= 1) m = fmaxf(m, __shfl_xor(m, d, 64));
    float sum = 0.f;
#pragma unroll
    for (int j = 0; j < 8; ++j) sum += __expf(v[j] - m);
#pragma unroll
    for (int d = 1; d < 8; d <<= 1) sum += __shfl_xor(sum, d, 64);
    float ls = m + logf(sum);

    float4 o0, o1;
    o0.x = v[0] - ls; o0.y = v[1] - ls; o0.z = v[2] - ls; o0.w = v[3] - ls;
    o1.x = v[4] - ls; o1.y = v[5] - ls; o1.z = v[6] - ls; o1.w = v[7] - ls;
    float4* out4 = (float4*)out;
    out4[(size_t)node * 16 + lr * 2]     = o0;
    out4[(size_t)node * 16 + lr * 2 + 1] = o1;
}

// ---------------- MFMA dual GEMM (layers 1-2), swapped operands --------------
// out[m][o] = sum_k [mean|h][m][k] * W[o][k] + b[o], ReLU, bf16 store.
// K=256 (mean 0-127, h 128-255), HO=128. Wave: 32 rows; block: 128 rows.
__global__ __launch_bounds__(256)
void sage_mfma2_kernel(const ushort* __restrict__ Amean, const ushort* __restrict__ Ah,
                       const ushort* __restrict__ Wf, const float* __restrict__ bias,
                       ushort* __restrict__ out, int n) {
    int wid = threadIdx.x >> 6, lane = threadIdx.x & 63;
    int rowbase = blockIdx.x * 128 + wid * 32;
    int lr = lane & 15, kg = lane >> 4;

    // hoist ALL A fragments: a[mr][ks], 16 independent loads in flight
    short8 a[2][8];
#pragma unroll
    for (int mr = 0; mr < 2; ++mr) {
        int r = rowbase + mr * 16 + lr;
        if (r > n - 1) r = n - 1;
#pragma unroll
        for (int ks = 0; ks < 8; ++ks) {
            const ushort* Asrc = (ks < 4) ? Amean : Ah;
            int koff = (ks & 3) * 32 + kg * 8;
            a[mr][ks] = *(const short8*)&Asrc[(size_t)r * 128 + koff];
        }
    }

#pragma unroll
    for (int half = 0; half < 2; ++half) {
        f32x4 acc[2][4];
#pragma unroll
        for (int mr = 0; mr < 2; ++mr)
#pragma unroll
            for (int c = 0; c < 4; ++c)
#pragma unroll
                for (int j = 0; j < 4; ++j) acc[mr][c][j] = 0.f;

#pragma unroll
        for (int c = 0; c < 4; ++c) {
            int ct = half * 4 + c;
            short8 w[8];
#pragma unroll
            for (int ks = 0; ks < 8; ++ks)
                w[ks] = *(const short8*)&Wf[(size_t)((ct * 8 + ks) * 64 + lane) * 8];
#pragma unroll
            for (int ks = 0; ks < 8; ++ks)
#pragma unroll
                for (int mr = 0; mr < 2; ++mr)
                    acc[mr][c] = __builtin_amdgcn_mfma_f32_16x16x32_bf16(w[ks], a[mr][ks], acc[mr][c], 0, 0, 0);
        }

        // epilogue: lane writes rows lr (+mr*16), cols ct*16 + kg*4 + 0..3
#pragma unroll
        for (int mr = 0; mr < 2; ++mr) {
            int r = rowbase + mr * 16 + lr;
            if (r < n) {
#pragma unroll
                for (int c = 0; c < 4; ++c) {
                    int col = (half * 4 + c) * 16 + kg * 4;
                    float4 b4 = *(const float4*)&bias[col];
                    float v0 = fmaxf(acc[mr][c][0] + b4.x, 0.f);
                    float v1 = fmaxf(acc[mr][c][1] + b4.y, 0.f);
                    float v2 = fmaxf(acc[mr][c][2] + b4.z, 0.f);
                    float v3 = fmaxf(acc[mr][c][3] + b4.w, 0.f);
                    uint2 o;
                    o.x = pack2bf(v0, v1);
                    o.y = pack2bf(v2, v3);
                    *(uint2*)&out[(size_t)r * 128 + col] = o;
                }
            }
        }
    }
}

// ---------------- layer-3 transform GEMM: p = h@W2l^T, q = h@W2r^T + b2 ------
// Wf3 fragment-major of stacked [W2l;W2r]; K=128; ct 0-3 -> p, 4-7 -> q.
__global__ __launch_bounds__(256)
void gemm3_kernel(const ushort* __restrict__ Ah, const ushort* __restrict__ Wf3,
                  const float* __restrict__ b2, ushort* __restrict__ p,
                  ushort* __restrict__ q, int n) {
    int wid = threadIdx.x >> 6, lane = threadIdx.x & 63;
    int rowbase = blockIdx.x * 128 + wid * 32;
    int lr = lane & 15, kg = lane >> 4;

    short8 a[2][4];
#pragma unroll
    for (int mr = 0; mr < 2; ++mr) {
        int r = rowbase + mr * 16 + lr;
        if (r > n - 1) r = n - 1;
#pragma unroll
        for (int ks = 0; ks < 4; ++ks)
            a[mr][ks] = *(const short8*)&Ah[(size_t)r * 128 + ks * 32 + kg * 8];
    }

    f32x4 acc[2][8];
#pragma unroll
    for (int mr = 0; mr < 2; ++mr)
#pragma unroll
        for (int ct = 0; ct < 8; ++ct)
#pragma unroll
            for (int j = 0; j < 4; ++j) acc[mr][ct][j] = 0.f;

#pragma unroll
    for (int ct = 0; ct < 8; ++ct) {
        short8 w[4];
#pragma unroll
        for (int ks = 0; ks < 4; ++ks)
            w[ks] = *(const short8*)&Wf3[(size_t)((ct * 4 + ks) * 64 + lane) * 8];
#pragma unroll
        for (int ks = 0; ks < 4; ++ks)
#pragma unroll
            for (int mr = 0; mr < 2; ++mr)
                acc[mr][ct] = __builtin_amdgcn_mfma_f32_16x16x32_bf16(w[ks], a[mr][ks], acc[mr][ct], 0, 0, 0);
    }

#pragma unroll
    for (int mr = 0; mr < 2; ++mr) {
        int r = rowbase + mr * 16 + lr;
        if (r >= n) continue;
#pragma unroll
        for (int ct = 0; ct < 8; ++ct) {
            bool isq = (ct >= 4);
            int col = (isq ? (ct - 4) : ct) * 16 + kg * 4;
            float b0 = 0.f, b1 = 0.f, b2v = 0.f, b3 = 0.f;
            if (isq) {
                float4 b4 = *(const float4*)&b2[col];
                b0 = b4.x; b1 = b4.y; b2v = b4.z; b3 = b4.w;
            }
            uint2 o;
            o.x = pack2bf(acc[mr][ct][0] + b0, acc[mr][ct][1] + b1);
            o.y = pack2bf(acc[mr][ct][2] + b2v, acc[mr][ct][3] + b3);
            ushort* dstp = isq ? q : p;
            *(uint2*)&dstp[(size_t)r * 64 + col] = o;
        }
    }
}

extern "C" void kernel_launch(void* const* d_in, const int* in_sizes, int n_in,
                              void* d_out, int out_size, void* d_ws, size_t ws_size,
                              hipStream_t stream) {
    const float* x   = (const float*)d_in[0];
    const int*   ei  = (const int*)d_in[1];
    const float* W0l = (const float*)d_in[2];
    const float* b0  = (const float*)d_in[3];
    const float* W0r = (const float*)d_in[4];
    const float* W1l = (const float*)d_in[5];
    const float* b1  = (const float*)d_in[6];
    const float* W1r = (const float*)d_in[7];
    const float* W2l = (const float*)d_in[8];
    const float* b2  = (const float*)d_in[9];
    const float* W2r = (const float*)d_in[10];

    int n = in_sizes[0] / N_FEAT;       // 100000
    int E = in_sizes[1] / 2;            // 1600000
    const int* srcv = ei;
    const int* dstv = ei + E;
    int NB = (n + 255) >> 8;            // coarse buckets (width 256 nodes)

    // workspace layout
    char* ws = (char*)d_ws;
    int* off     = (int*)ws;                 // n+1
    int* csr     = off + (n + 1);            // E
    int* btot    = csr + E;                  // NB
    int* bbase   = btot + NBMAX;             // NB+1
    int* gcursor = bbase + NBMAX + 1;        // NB
    size_t intbytes = ((size_t)(n + 1) + E + 3 * NBMAX + 1) * sizeof(int);
    intbytes = (intbytes + 255) & ~(size_t)255;
    ushort* xbf   = (ushort*)(ws + intbytes);       // n*128 bf16
    ushort* meanb = xbf + (size_t)n * N_FEAT;       // n*128  (also: bucketArr, p3|q3)
    ushort* hA    = meanb + (size_t)n * N_FEAT;     // n*128
    ushort* hB    = hA + (size_t)n * N_FEAT;        // n*128
    ushort* wcat0 = hB + (size_t)n * N_FEAT;        // 8*8*64*8 = 32768
    ushort* wcat1 = wcat0 + 32768;                  // 32768
    ushort* wcat3 = wcat1 + 32768;                  // 8*4*64*8 = 16384

    uint* bucketArr = (uint*)meanb;                 // E * 4B, used only during CSR build
    ushort* p3 = meanb;                             // n*64 bf16
    ushort* q3 = meanb + (size_t)n * 64;            // n*64 bf16

    int ebGrid = (E + SCHUNK - 1) / SCHUNK;

    // ---- build CSR (bucketed counting sort, packed entries) ----
    hipMemsetAsync(btot, 0, (size_t)NBMAX * sizeof(int), stream);
    bucket_hist_kernel<<<ebGrid, 256, 0, stream>>>(dstv, btot, E, NB);
    bucket_scan_kernel<<<1, 512, 0, stream>>>(btot, bbase, gcursor, NB, off, n);
    bucket_scatter_kernel<<<ebGrid, 256, 0, stream>>>(srcv, dstv, gcursor, bucketArr, E, NB);
    bucket_build_kernel<<<NB, 256, 0, stream>>>(bucketArr, bbase, off, csr, n);

    // ---- convert x and weights to bf16 (fragment-major W) ----
    int total8 = n * N_FEAT / 8;
    f32_to_bf16_kernel<<<(total8 + 255) / 256, 256, 0, stream>>>(x, (uint4*)xbf, total8);
    wcatF_kernel<<<16, 256, 0, stream>>>(W0l, W0r, wcat0);
    wcatF_kernel<<<16, 256, 0, stream>>>(W1l, W1r, wcat1);
    wcat3F_kernel<<<8, 256, 0, stream>>>(W2l, W2r, wcat3);

    int agg128Grid = (n + 15) / 16;
    int gemmGrid = (n + 127) / 128;

    // ---- layer 1 ----
    aggregate128_kernel<<<agg128Grid, 256, 0, stream>>>((const uint4*)xbf, off, csr, (uint4*)meanb, n);
    sage_mfma2_kernel<<<gemmGrid, 256, 0, stream>>>(meanb, xbf, wcat0, b0, hA, n);
    // ---- layer 2 ----
    aggregate128_kernel<<<agg128Grid, 256, 0, stream>>>((const uint4*)hA, off, csr, (uint4*)meanb, n);
    sage_mfma2_kernel<<<gemmGrid, 256, 0, stream>>>(meanb, hA, wcat1, b1, hB, n);
    // ---- layer 3: transform, aggregate 64-wide + fused add/log_softmax ----
    gemm3_kernel<<<gemmGrid, 256, 0, stream>>>(hB, wcat3, b2, p3, q3, n);
    agg64_ls_kernel<<<(n + 31) / 32, 256, 0, stream>>>((const uint4*)p3, off, csr,
                                                       (const uint4*)q3, (float*)d_out, n);
}